// Round 6
// baseline (292.532 us; speedup 1.0000x reference)
//
#include <hip/hip_runtime.h>
#include <math.h>

#define DIMV 2048
#define NHEAD 16
#define NKV 8
#define HD 128
#define BATCH 2
#define SEQ 2048
#define CHUNK 128
#define NCHUNK 16
#define MTOK 4096  // BATCH*SEQ
#define KVD (NKV * HD)  // 1024

typedef _Float16 half8_t __attribute__((ext_vector_type(8)));
typedef _Float16 half4_t __attribute__((ext_vector_type(4)));
typedef _Float16 half2_t __attribute__((ext_vector_type(2)));
typedef float f32x4 __attribute__((ext_vector_type(4)));

#define GLOBAL_AS __attribute__((address_space(1)))
#define LDS_AS __attribute__((address_space(3)))

#define BARX() __builtin_amdgcn_s_barrier()
#define WAITL(n) asm volatile("s_waitcnt lgkmcnt(" #n ")" ::: "memory")
#define WAITVM(n) asm volatile("s_waitcnt vmcnt(" #n ")" ::: "memory")

// ---------------------------------------------------------------------------
// All five f32->f16 casts + fc transpose in one launch. grid 10304 x 256.
// Blocks >= 10240 run the fc[2048][128] -> fcT[128][2048] tile transpose.
// ---------------------------------------------------------------------------
__global__ __launch_bounds__(256) void cast_all(const float* __restrict__ x,
                                                const float* __restrict__ wq,
                                                const float* __restrict__ wk,
                                                const float* __restrict__ wv,
                                                const float* __restrict__ wo,
                                                _Float16* __restrict__ xh,
                                                _Float16* __restrict__ wqkvh,
                                                _Float16* __restrict__ woh,
                                                const float* __restrict__ fc,
                                                float* __restrict__ fcT) {
  __shared__ float T[64][65];
  if (blockIdx.x >= 10240) {
    int q = blockIdx.x - 10240;            // 64 tail blocks = old dim3(32,2)
    int s0 = (q & 31) * 64, d0 = (q >> 5) * 64;
    int t = threadIdx.x;
    int r = t >> 4, c4 = (t & 15) * 4;
#pragma unroll
    for (int p = 0; p < 4; ++p) {
      int sr = p * 16 + r;
      float4 v = *(const float4*)&fc[(size_t)(s0 + sr) * 128 + d0 + c4];
      T[sr][c4] = v.x; T[sr][c4 + 1] = v.y; T[sr][c4 + 2] = v.z; T[sr][c4 + 3] = v.w;
    }
    __syncthreads();
#pragma unroll
    for (int p = 0; p < 4; ++p) {
      int dr = p * 16 + r;
      float4 v = make_float4(T[c4][dr], T[c4 + 1][dr], T[c4 + 2][dr], T[c4 + 3][dr]);
      *(float4*)&fcT[(size_t)(d0 + dr) * SEQ + s0 + c4] = v;
    }
    return;
  }
  long i = (long)(blockIdx.x * 256 + threadIdx.x) * 8;
  const float* src;
  _Float16* dst;
  long off;
  if (i < 8388608)        { src = x;  dst = xh;              off = 0; }
  else if (i < 12582912)  { src = wq; dst = wqkvh;           off = 8388608; }
  else if (i < 14680064)  { src = wk; dst = wqkvh + 4194304; off = 12582912; }
  else if (i < 16777216)  { src = wv; dst = wqkvh + 6291456; off = 14680064; }
  else                    { src = wo; dst = woh;             off = 16777216; }
  long e = i - off;
  float4 a = *(const float4*)&src[e];
  float4 b = *(const float4*)&src[e + 4];
  half8_t h = {(_Float16)a.x, (_Float16)a.y, (_Float16)a.z, (_Float16)a.w,
               (_Float16)b.x, (_Float16)b.y, (_Float16)b.z, (_Float16)b.w};
  *(half8_t*)&dst[e] = h;
}

// ---------------------------------------------------------------------------
// Fused QKV projection, 256x256 tile, BK=64, 8-phase counted-vmcnt schedule.
// (Round-2 verified: 82 us at full clock, 0 bank conflicts.)
// ---------------------------------------------------------------------------
#define STG_A(bb, kk, i, k0)                                                      \
  __builtin_amdgcn_global_load_lds(                                               \
      (const GLOBAL_AS void*)(A + aoff + (size_t)(i) * 128 * 2048 + (k0) + (kk) * 32), \
      (LDS_AS void*)(As + ((bb) * 2 + (kk)) * 8192 + (i) * 4096 + wave * 512), 16, 0, 0)
#define STG_B(bb, kk, i, k0)                                                      \
  __builtin_amdgcn_global_load_lds(                                               \
      (const GLOBAL_AS void*)(B + boff + (size_t)(i) * 128 * 2048 + (k0) + (kk) * 32), \
      (LDS_AS void*)(Bs + ((bb) * 2 + (kk)) * 8192 + (i) * 4096 + wave * 512), 16, 0, 0)

#define LDA_F(bb, kk, ih) do {                                                    \
    const _Float16* pA_ = As + ((bb) * 2 + (kk)) * 8192 +                         \
                          (wr * 128 + (ih) * 64 + m16) * 32 + pseg8;              \
    af[0] = *(const half8_t*)(pA_);                                               \
    af[1] = *(const half8_t*)(pA_ + 512);                                         \
    af[2] = *(const half8_t*)(pA_ + 1024);                                        \
    af[3] = *(const half8_t*)(pA_ + 1536);                                        \
  } while (0)
#define LDB_F(bb, kk) do {                                                        \
    const _Float16* pB_ = Bs + ((bb) * 2 + (kk)) * 8192 +                         \
                          (wc * 64 + m16) * 32 + pseg8;                           \
    bf[0] = *(const half8_t*)(pB_);                                               \
    bf[1] = *(const half8_t*)(pB_ + 512);                                         \
    bf[2] = *(const half8_t*)(pB_ + 1024);                                        \
    bf[3] = *(const half8_t*)(pB_ + 1536);                                        \
  } while (0)

#define MMX(ih) do {                                                              \
    _Pragma("unroll")                                                             \
    for (int i_ = 0; i_ < 4; ++i_)                                                \
      _Pragma("unroll")                                                           \
      for (int j_ = 0; j_ < 4; ++j_)                                              \
        acc[(ih) * 4 + i_][j_] = __builtin_amdgcn_mfma_f32_16x16x32_f16(          \
            af[i_], bf[j_], acc[(ih) * 4 + i_][j_], 0, 0, 0);                     \
  } while (0)

#define KTILE(bb, k0, DS1, DS2, DS3, DS4, VA, VB) do {                            \
  half8_t af[4], bf[4];                                                           \
  LDA_F(bb, 0, 0); LDB_F(bb, 0);                                                  \
  if (DS1) { STG_A(1 - (bb), 1, 0, (k0) + 64); STG_A(1 - (bb), 1, 1, (k0) + 64); } \
  BARX(); WAITL(0);                                                               \
  __builtin_amdgcn_s_setprio(1); MMX(0); __builtin_amdgcn_s_setprio(0);           \
  BARX();                                                                         \
  LDA_F(bb, 0, 1);                                                                \
  if (DS2) { STG_B(1 - (bb), 1, 0, (k0) + 64); STG_B(1 - (bb), 1, 1, (k0) + 64); } \
  WAITVM(VA);                                                                     \
  BARX(); WAITL(0);                                                               \
  __builtin_amdgcn_s_setprio(1); MMX(1); __builtin_amdgcn_s_setprio(0);           \
  BARX();                                                                         \
  LDA_F(bb, 1, 0); LDB_F(bb, 1);                                                  \
  if (DS3) { STG_A(bb, 0, 0, (k0) + 128); STG_A(bb, 0, 1, (k0) + 128); }          \
  BARX(); WAITL(0);                                                               \
  __builtin_amdgcn_s_setprio(1); MMX(0); __builtin_amdgcn_s_setprio(0);           \
  BARX();                                                                         \
  LDA_F(bb, 1, 1);                                                                \
  if (DS4) { STG_B(bb, 0, 0, (k0) + 128); STG_B(bb, 0, 1, (k0) + 128); }          \
  WAITVM(VB);                                                                     \
  BARX(); WAITL(0);                                                               \
  __builtin_amdgcn_s_setprio(1); MMX(1); __builtin_amdgcn_s_setprio(0);           \
  BARX();                                                                         \
} while (0)

__global__ __launch_bounds__(512, 2) void hgemm_qkv_8p(const _Float16* __restrict__ A,
                                                       const _Float16* __restrict__ B,
                                                       const float* __restrict__ fc,
                                                       _Float16* __restrict__ qh,
                                                       _Float16* __restrict__ kT,
                                                       _Float16* __restrict__ vT) {
  const int K = 2048;
  __shared__ _Float16 As[32768];  // [buf][kk][256][32]
  __shared__ _Float16 Bs[32768];
  __shared__ float qsum[4][256];

  const int tid = threadIdx.x;
  const int lane = tid & 63;
  const int wave = tid >> 6;
  const int wr = wave >> 2;
  const int wc = wave & 3;
  const int m16 = lane & 15, quad = lane >> 4;
  const int row0 = blockIdx.y * 256, col0 = blockIdx.x * 256;
  const int pseg8 = (quad ^ ((m16 >> 1) & 3)) * 8;

  const int r_ld = tid >> 2;
  const int sseg = (tid & 3) ^ ((tid >> 3) & 3);
  const size_t aoff = (size_t)(row0 + r_ld) * K + sseg * 8;
  const size_t boff = (size_t)(col0 + r_ld) * K + sseg * 8;

  f32x4 acc[8][4];
#pragma unroll
  for (int m = 0; m < 8; ++m)
#pragma unroll
    for (int j = 0; j < 4; ++j) acc[m][j] = (f32x4){0.f, 0.f, 0.f, 0.f};

  STG_A(0, 0, 0, 0); STG_A(0, 0, 1, 0); STG_B(0, 0, 0, 0); STG_B(0, 0, 1, 0);
  STG_A(0, 1, 0, 0); STG_A(0, 1, 1, 0); STG_B(0, 1, 0, 0); STG_B(0, 1, 1, 0);
  STG_A(1, 0, 0, 64); STG_A(1, 0, 1, 64); STG_B(1, 0, 0, 64); STG_B(1, 0, 1, 64);
  WAITVM(8);
  BARX();

  for (int t = 0; t < 30; t += 2) {
    KTILE(0, t * 64,      1, 1, 1, 1, 8, 8);
    KTILE(1, t * 64 + 64, 1, 1, 1, 1, 8, 8);
  }
  KTILE(0, 1920, 1, 1, 0, 0, 8, 4);
  KTILE(1, 1984, 0, 0, 0, 0, 0, 0);

  if (col0 < 2048) {
    const float sc = 0.08838834764831845f;  // 128^-0.5
    float psum[8][4];
#pragma unroll
    for (int m = 0; m < 8; ++m)
#pragma unroll
      for (int r = 0; r < 4; ++r) psum[m][r] = 0.f;
#pragma unroll
    for (int m = 0; m < 8; ++m)
#pragma unroll
      for (int j = 0; j < 4; ++j) {
        int dl2 = (wc * 64 + j * 16 + m16) & 126;
#pragma unroll
        for (int r = 0; r < 4; ++r) {
          float val = acc[m][j][r];
          float par = __shfl_xor(val, 1);
          int row_l = wr * 128 + (m >> 2) * 64 + (m & 3) * 16 + quad * 4 + r;
          int s_tok = (row0 + row_l) & (SEQ - 1);
          float2 cs = *(const float2*)&fc[(size_t)s_tok * 128 + dl2];
          float o = val * cs.x + par * ((m16 & 1) ? cs.y : -cs.y);
          float e = __expf(o * sc);
          acc[m][j][r] = e;
          psum[m][r] += e;
        }
      }
#pragma unroll
    for (int mm = 1; mm < 16; mm <<= 1)
#pragma unroll
      for (int m = 0; m < 8; ++m)
#pragma unroll
        for (int r = 0; r < 4; ++r) psum[m][r] += __shfl_xor(psum[m][r], mm);
    if (m16 == 0) {
#pragma unroll
      for (int m = 0; m < 8; ++m)
#pragma unroll
        for (int r = 0; r < 4; ++r) {
          int row_l = wr * 128 + (m >> 2) * 64 + (m & 3) * 16 + quad * 4 + r;
          qsum[wc][row_l] = psum[m][r];
        }
    }
    __syncthreads();
#pragma unroll
    for (int m = 0; m < 8; ++m)
#pragma unroll
      for (int r = 0; r < 4; ++r) {
        int row_l = wr * 128 + (m >> 2) * 64 + (m & 3) * 16 + quad * 4 + r;
        psum[m][r] = 1.f / (qsum[wc & 2][row_l] + qsum[(wc & 2) | 1][row_l]);
      }
#pragma unroll
    for (int m = 0; m < 8; ++m)
#pragma unroll
      for (int j = 0; j < 4; ++j) {
        int col = col0 + wc * 64 + j * 16 + m16;
#pragma unroll
        for (int r = 0; r < 4; ++r) {
          int row_l = wr * 128 + (m >> 2) * 64 + (m & 3) * 16 + quad * 4 + r;
          qh[(size_t)(row0 + row_l) * DIMV + col] = (_Float16)(acc[m][j][r] * psum[m][r]);
        }
      }
  } else {
#pragma unroll
    for (int m = 0; m < 8; ++m)
#pragma unroll
      for (int j = 0; j < 4; ++j) {
        int col = col0 + wc * 64 + j * 16 + m16;
        int rowb = row0 + wr * 128 + (m >> 2) * 64 + (m & 3) * 16 + quad * 4;
        half4_t hv = {(_Float16)acc[m][j][0], (_Float16)acc[m][j][1],
                      (_Float16)acc[m][j][2], (_Float16)acc[m][j][3]};
        if (col0 < 3072) {
          *(half4_t*)&kT[(size_t)(col - 2048) * MTOK + rowb] = hv;
        } else {
          *(half4_t*)&vT[(size_t)(col - 3072) * MTOK + rowb] = hv;
        }
      }
  }
}

// ---------------------------------------------------------------------------
// Output GEMM, KTILE-class schedule (round-5 verified win).
// ---------------------------------------------------------------------------
#define STGBT(bb, kk, k0) do {                                                    \
  __builtin_amdgcn_global_load_lds(                                               \
      (const GLOBAL_AS void*)(A + abase + (k0) + (kk) * 32),                      \
      (LDS_AS void*)(As + ((bb) * 2 + (kk)) * 4096 + wave * 512), 16, 0, 0);      \
  __builtin_amdgcn_global_load_lds(                                               \
      (const GLOBAL_AS void*)(B + bbase + (k0) + (kk) * 32),                      \
      (LDS_AS void*)(Bs + ((bb) * 2 + (kk)) * 8192 + wave * 512), 16, 0, 0);      \
  __builtin_amdgcn_global_load_lds(                                               \
      (const GLOBAL_AS void*)(B + bbase + (size_t)128 * 2048 + (k0) + (kk) * 32), \
      (LDS_AS void*)(Bs + ((bb) * 2 + (kk)) * 8192 + 4096 + wave * 512), 16, 0, 0);\
} while (0)

#define PHASE_BT(bb, kk, SEN, sbb, skk, sk0, VM) do {                             \
  WAITVM(VM);                                                                     \
  BARX();                                                                         \
  half8_t af[4], bf[4];                                                           \
  const _Float16* pA_ = As + ((bb) * 2 + (kk)) * 4096 +                           \
                        (wr * 64 + m16) * 32 + pseg8;                             \
  const _Float16* pB_ = Bs + ((bb) * 2 + (kk)) * 8192 +                           \
                        (wc * 64 + m16) * 32 + pseg8;                             \
  af[0] = *(const half8_t*)(pA_);        af[1] = *(const half8_t*)(pA_ + 512);    \
  af[2] = *(const half8_t*)(pA_ + 1024); af[3] = *(const half8_t*)(pA_ + 1536);   \
  bf[0] = *(const half8_t*)(pB_);        bf[1] = *(const half8_t*)(pB_ + 512);    \
  bf[2] = *(const half8_t*)(pB_ + 1024); bf[3] = *(const half8_t*)(pB_ + 1536);   \
  if (SEN) STGBT(sbb, skk, sk0);                                                  \
  WAITL(0);                                                                       \
  __builtin_amdgcn_s_setprio(1);                                                  \
  _Pragma("unroll")                                                               \
  for (int i_ = 0; i_ < 4; ++i_)                                                  \
    _Pragma("unroll")                                                             \
    for (int j_ = 0; j_ < 4; ++j_)                                                \
      acc[i_][j_] = __builtin_amdgcn_mfma_f32_16x16x32_f16(                       \
          af[i_], bf[j_], acc[i_][j_], 0, 0, 0);                                  \
  __builtin_amdgcn_s_setprio(0);                                                  \
} while (0)

__global__ __launch_bounds__(512, 2) void hgemm_bt_8p(const _Float16* __restrict__ A,
                                                      const _Float16* __restrict__ B,
                                                      float* __restrict__ C) {
  const int K = 2048, N = 2048;
  __shared__ _Float16 As[16384];  // [buf][kk][128][32]
  __shared__ _Float16 Bs[32768];  // [buf][kk][256][32]

  const int tid = threadIdx.x;
  const int lane = tid & 63;
  const int wave = tid >> 6;
  const int wr = wave >> 2;
  const int wc = wave & 3;
  const int m16 = lane & 15, quad = lane >> 4;
  const int row0 = blockIdx.y * 128, col0 = blockIdx.x * 256;
  const int pseg8 = (quad ^ ((m16 >> 1) & 3)) * 8;

  const int r_ld = tid >> 2;
  const int sseg = (tid & 3) ^ ((tid >> 3) & 3);
  const size_t abase = (size_t)(row0 + r_ld) * K + sseg * 8;
  const size_t bbase = (size_t)(col0 + r_ld) * K + sseg * 8;

  f32x4 acc[4][4];
#pragma unroll
  for (int i = 0; i < 4; ++i)
#pragma unroll
    for (int j = 0; j < 4; ++j) acc[i][j] = (f32x4){0.f, 0.f, 0.f, 0.f};

  STGBT(0, 0, 0); STGBT(0, 1, 0); STGBT(1, 0, 64);

  for (int t = 0; t < 30; ++t) {
    const int bb = t & 1;
    const int k0 = t * 64;
    PHASE_BT(bb, 0, 1, bb ^ 1, 1, k0 + 64, 6);
    PHASE_BT(bb, 1, 1, bb, 0, k0 + 128, 6);
  }
  PHASE_BT(0, 0, 1, 1, 1, 1984, 6);
  PHASE_BT(0, 1, 0, 0, 0, 0, 6);
  PHASE_BT(1, 0, 0, 0, 0, 0, 3);
  PHASE_BT(1, 1, 0, 0, 0, 0, 0);

#pragma unroll
  for (int i = 0; i < 4; ++i)
#pragma unroll
    for (int j = 0; j < 4; ++j) {
      int col = col0 + wc * 64 + j * 16 + m16;
      int rowb = row0 + wr * 64 + i * 16 + quad * 4;
#pragma unroll
      for (int r = 0; r < 4; ++r) C[(size_t)(rowb + r) * N + col] = acc[i][j][r];
    }
}

// ---------------------------------------------------------------------------
// k_finalize: RoPE + token-softmax + dual-layout write, fused.
// One block = (b, 16-dim group). Pass 1: rope+exp (f32) -> LDS + per-dim sums.
// Pass 2a: normalize -> kT (dim-major, coalesced half8).
// Pass 2b: normalize -> kh (token-major, 2x half8 per token).
// LDS ~131.6 KB -> 1 block/CU. grid 128 x 256.
// ---------------------------------------------------------------------------
__global__ __launch_bounds__(256) void k_finalize(_Float16* __restrict__ kT,
                                                  _Float16* __restrict__ kh,
                                                  const float* __restrict__ fcT) {
  __shared__ float T[16][2052];   // [dim][token], +4 pad
  __shared__ float red[64];       // [pair][wave][parity] = [8][4][2]
  __shared__ float inv_s[16];
  const int bi = blockIdx.x;
  const int b = bi & 1, dg = bi >> 1;     // dg 0..63
  const int d0 = dg * 16;                 // global kv-dim base (even, 16-aligned)
  const int t = threadIdx.x;
  const int wv = t >> 6;
  const int s8 = t * 8;

#pragma unroll
  for (int pr = 0; pr < 8; ++pr) {
    const int da = d0 + pr * 2;
    const int dla = da & 127;             // head-local (even)
    size_t r0 = (size_t)da * MTOK + b * SEQ + s8;
    half8_t x0v = *(const half8_t*)&kT[r0];
    half8_t x1v = *(const half8_t*)&kT[r0 + MTOK];
    float4 ca = *(const float4*)&fcT[(size_t)dla * SEQ + s8];
    float4 cb = *(const float4*)&fcT[(size_t)dla * SEQ + s8 + 4];
    float4 sa = *(const float4*)&fcT[(size_t)(dla + 1) * SEQ + s8];
    float4 sb = *(const float4*)&fcT[(size_t)(dla + 1) * SEQ + s8 + 4];
    float cc[8] = {ca.x, ca.y, ca.z, ca.w, cb.x, cb.y, cb.z, cb.w};
    float ss[8] = {sa.x, sa.y, sa.z, sa.w, sb.x, sb.y, sb.z, sb.w};
    float sum0 = 0.f, sum1 = 0.f;
#pragma unroll
    for (int j = 0; j < 8; ++j) {
      float x0 = (float)x0v[j], x1 = (float)x1v[j];
      float o0 = x0 * cc[j] - x1 * ss[j];
      float o1 = x0 * ss[j] + x1 * cc[j];
      float e0 = expf(o0), e1 = expf(o1);
      T[pr * 2][s8 + j] = e0;
      T[pr * 2 + 1][s8 + j] = e1;
      sum0 += e0; sum1 += e1;
    }
#pragma unroll
    for (int off = 1; off < 64; off <<= 1) {
      sum0 += __shfl_xor(sum0, off);
      sum1 += __shfl_xor(sum1, off);
    }
    if ((t & 63) == 0) {
      red[pr * 8 + wv * 2] = sum0;
      red[pr * 8 + wv * 2 + 1] = sum1;
    }
  }
  __syncthreads();
  if (t < 16) {
    int pr = t >> 1, par = t & 1;
    float den = red[pr * 8 + par] + red[pr * 8 + 2 + par] +
                red[pr * 8 + 4 + par] + red[pr * 8 + 6 + par];
    inv_s[t] = 1.f / den;
  }
  __syncthreads();

  // pass 2a: normalized -> kT (coalesced per dim row)
#pragma unroll
  for (int d = 0; d < 16; ++d) {
    float iv = inv_s[d];
    half8_t w;
#pragma unroll
    for (int j = 0; j < 8; ++j) w[j] = (_Float16)(T[d][s8 + j] * iv);
    *(half8_t*)&kT[(size_t)(d0 + d) * MTOK + b * SEQ + s8] = w;
  }
  // pass 2b: normalized -> kh (token-major; 2 half8 per token)
  float iv[16];
#pragma unroll
  for (int d = 0; d < 16; ++d) iv[d] = inv_s[d];
#pragma unroll
  for (int jj = 0; jj < 8; ++jj) {
    int tok = jj * 256 + t;
    half8_t wa, wb;
#pragma unroll
    for (int d = 0; d < 8; ++d) {
      wa[d] = (_Float16)(T[d][tok] * iv[d]);
      wb[d] = (_Float16)(T[d + 8][tok] * iv[d + 8]);
    }
    size_t o = (size_t)(b * SEQ + tok) * KVD + d0;
    *(half8_t*)&kh[o] = wa;
    *(half8_t*)&kh[o + 8] = wb;
  }
}

// ---------------------------------------------------------------------------
// kv_cum: fused per-chunk kv outer product + exclusive chunk-cumsum.
// One block = (b, kvh, e-half, d-half): 64x64 output slice, 16 chunks
// sequential, running cumsum in registers, writes cumh directly (exclusive).
// Double-buffered LDS (2x32KB), counted vmcnt, XOR-swizzled tiles.
// grid 64 x 256.
// ---------------------------------------------------------------------------
#define KVSTG(buf, n) do {                                                        \
  const size_t t0_ = (size_t)b * SEQ + (size_t)(n) * CHUNK;                       \
  _Pragma("unroll")                                                               \
  for (int i_ = 0; i_ < 4; ++i_) {                                                \
    __builtin_amdgcn_global_load_lds(                                             \
        (const GLOBAL_AS void*)(vT + (size_t)(e0 + i_ * 16 + rhi) * MTOK + t0_ + slog * 8), \
        (LDS_AS void*)(Vs + (buf) * 8192 + i_ * 2048 + wave * 512), 16, 0, 0);    \
    __builtin_amdgcn_global_load_lds(                                             \
        (const GLOBAL_AS void*)(kT + (size_t)(d0 + i_ * 16 + rhi) * MTOK + t0_ + slog * 8), \
        (LDS_AS void*)(Ks + (buf) * 8192 + i_ * 2048 + wave * 512), 16, 0, 0);    \
  }                                                                               \
} while (0)

__global__ __launch_bounds__(256) void kv_cum(const _Float16* __restrict__ vT,
                                              const _Float16* __restrict__ kT,
                                              _Float16* __restrict__ cumh) {
  __shared__ _Float16 Vs[2 * 8192];  // [buf][64][128]
  __shared__ _Float16 Ks[2 * 8192];
  const int bi = blockIdx.x;
  const int eh = bi & 1, dh = (bi >> 1) & 1, kvh = (bi >> 2) & 7, b = bi >> 5;
  const int e0 = kvh * HD + eh * 64;
  const int d0 = kvh * HD + dh * 64;
  const int tid = threadIdx.x;
  const int lane = tid & 63;
  const int wave = tid >> 6;
  const int wr = wave >> 1, wcd = wave & 1;  // 32x32 per wave
  const int m16 = lane & 15, quad = lane >> 4;

  // staging: row-within-16 = tid>>4, phys seg = tid&15, logical = phys ^ row16
  const int rhi = tid >> 4;                  // 0..15
  const int slog = (tid & 15) ^ rhi;

  const size_t cbase0 = ((size_t)(b * 8 + kvh) * 16) * 16384;
  const int erel = eh * 64 + wr * 32;
  const int drel = dh * 64 + wcd * 32;

  f32x4 run[2][2];
#pragma unroll
  for (int i = 0; i < 2; ++i)
#pragma unroll
    for (int j = 0; j < 2; ++j) run[i][j] = (f32x4){0.f, 0.f, 0.f, 0.f};

  KVSTG(0, 0);
  KVSTG(1, 1);

#pragma unroll
  for (int n = 0; n < NCHUNK; ++n) {
    if (n < 15) { WAITVM(8); } else { WAITVM(0); }
    BARX();
    // write exclusive cumsum for chunk n (run holds sum of chunks < n)
    {
      size_t cb = cbase0 + (size_t)n * 16384;
#pragma unroll
      for (int i = 0; i < 2; ++i)
#pragma unroll
        for (int j = 0; j < 2; ++j)
#pragma unroll
          for (int r = 0; r < 4; ++r) {
            int e = erel + i * 16 + quad * 4 + r;
            int d = drel + j * 16 + m16;
            cumh[cb + (size_t)e * 128 + d] = (_Float16)run[i][j][r];
          }
    }
    const _Float16* rv = Vs + (n & 1) * 8192;
    const _Float16* rk = Ks + (n & 1) * 8192;
    f32x4 acc[2][2];
#pragma unroll
    for (int i = 0; i < 2; ++i)
#pragma unroll
      for (int j = 0; j < 2; ++j) acc[i][j] = (f32x4){0.f, 0.f, 0.f, 0.f};
#pragma unroll
    for (int ks = 0; ks < 4; ++ks) {
      half8_t af[2], bf[2];
#pragma unroll
      for (int i = 0; i < 2; ++i) {
        int rowv = wr * 32 + i * 16 + m16;
        int rowk = wcd * 32 + i * 16 + m16;
        int ps = (ks * 4 + quad) ^ m16;   // row&15 == m16
        af[i] = *(const half8_t*)&rv[rowv * 128 + ps * 8];
        bf[i] = *(const half8_t*)&rk[rowk * 128 + ps * 8];
      }
#pragma unroll
      for (int i = 0; i < 2; ++i)
#pragma unroll
        for (int j = 0; j < 2; ++j)
          acc[i][j] = __builtin_amdgcn_mfma_f32_16x16x32_f16(af[i], bf[j], acc[i][j], 0, 0, 0);
    }
#pragma unroll
    for (int i = 0; i < 2; ++i)
#pragma unroll
      for (int j = 0; j < 2; ++j) run[i][j] += acc[i][j];
    BARX();
    if (n < 14) KVSTG(n & 1, n + 2);
  }
}

// ---------------------------------------------------------------------------
// Fused scores+output per (b,h,chunk). q staged once in swizzled Qs;
// B-side double-buffered; 12 uniform steps; Ss swizzled. LDS 80KB.
// ---------------------------------------------------------------------------
__global__ __launch_bounds__(256) void attn_fused(const _Float16* __restrict__ qh,
                                                  const _Float16* __restrict__ kh,
                                                  const _Float16* __restrict__ cumh,
                                                  const _Float16* __restrict__ vT,
                                                  _Float16* __restrict__ ath) {
  __shared__ _Float16 Qs[128 * 128];
  __shared__ _Float16 Bs[2][128 * 32];
  __shared__ _Float16 Ss[128 * 128];
  int bi = blockIdx.x;
  int n = bi & 15, h = (bi >> 4) & 15, b = bi >> 8;
  int kvh = h >> 1;
  int tok0 = b * SEQ + n * CHUNK;
  const int tid = threadIdx.x;
  const int lane = tid & 63;
  const int wave = tid >> 6;
  const int wr = wave & 1, wc = wave >> 1;
  const int m16 = lane & 15, quad = lane >> 4;
  const int qsw8 = (quad ^ ((m16 >> 1) & 3)) * 8;
  const int r_ld = tid >> 2;
  const int sseg = (tid & 3) ^ ((tid >> 3) & 3);

  f32x4 acc[4][4];
#pragma unroll
  for (int i = 0; i < 4; ++i)
#pragma unroll
    for (int j = 0; j < 4; ++j) acc[i][j] = (f32x4){0.f, 0.f, 0.f, 0.f};

  const int qrow = tid >> 4;
  const int qsl = (tid & 15) ^ (qrow & 7);
  const size_t qsrc = (size_t)(tok0 + qrow) * DIMV + h * HD + qsl * 8;
#pragma unroll
  for (int p = 0; p < 8; ++p)
    __builtin_amdgcn_global_load_lds(
        (const GLOBAL_AS void*)(qh + qsrc + (size_t)p * 16 * DIMV),
        (LDS_AS void*)(Qs + p * 2048 + wave * 512), 16, 0, 0);

  const size_t kbase = (size_t)(tok0 + r_ld) * KVD + kvh * HD + sseg * 8;
  const size_t cbase = ((size_t)((b * 8 + kvh) * 16 + n)) * 16384 + (size_t)r_ld * 128 + sseg * 8;
  const size_t vbase = (size_t)(kvh * HD + r_ld) * MTOK + tok0 + sseg * 8;

#pragma unroll
  for (int i = 0; i < 2; ++i)
    __builtin_amdgcn_global_load_lds(
        (const GLOBAL_AS void*)(kh + kbase + (size_t)i * 64 * KVD),
        (LDS_AS void*)(&Bs[0][0] + i * 2048 + wave * 512), 16, 0, 0);

#pragma unroll
  for (int s = 0; s < 12; ++s) {
    WAITVM(0);
    BARX();
    if (s < 11) {
      const int sn = s + 1;
      _Float16* dstB = &Bs[sn & 1][0];
      if (sn < 4) {
        const int k0 = sn * 32;
#pragma unroll
        for (int i = 0; i < 2; ++i)
          __builtin_amdgcn_global_load_lds(
              (const GLOBAL_AS void*)(kh + kbase + (size_t)i * 64 * KVD + k0),
              (LDS_AS void*)(dstB + i * 2048 + wave * 512), 16, 0, 0);
      } else if (sn < 8) {
        const int k0 = (sn - 4) * 32;
#pragma unroll
        for (int i = 0; i < 2; ++i)
          __builtin_amdgcn_global_load_lds(
              (const GLOBAL_AS void*)(cumh + cbase + (size_t)i * 64 * 128 + k0),
              (LDS_AS void*)(dstB + i * 2048 + wave * 512), 16, 0, 0);
      } else {
        const int k0 = (sn - 8) * 32;
#pragma unroll
        for (int i = 0; i < 2; ++i)
          __builtin_amdgcn_global_load_lds(
              (const GLOBAL_AS void*)(vT + vbase + (size_t)i * 64 * MTOK + k0),
              (LDS_AS void*)(dstB + i * 2048 + wave * 512), 16, 0, 0);
      }
    }
    half8_t af[4], bf[4];
    const _Float16* rb = &Bs[s & 1][0];
#pragma unroll
    for (int i = 0; i < 4; ++i)
      bf[i] = *(const half8_t*)&rb[(wc * 64 + i * 16 + m16) * 32 + qsw8];
    if (s < 8) {
      const int sl4 = (s & 3) * 4;
#pragma unroll
      for (int i = 0; i < 4; ++i) {
        int row = wr * 64 + i * 16 + m16;
        af[i] = *(const half8_t*)&Qs[row * 128 + ((sl4 + quad) ^ (m16 & 7)) * 8];
      }
    } else {
      const int sl4 = (s - 8) * 4;
#pragma unroll
      for (int i = 0; i < 4; ++i) {
        int row = wr * 64 + i * 16 + m16;
        af[i] = *(const half8_t*)&Ss[row * 128 + ((sl4 + quad) ^ (m16 & 7)) * 8];
      }
    }
#pragma unroll
    for (int i = 0; i < 4; ++i)
#pragma unroll
      for (int j = 0; j < 4; ++j)
        acc[i][j] = __builtin_amdgcn_mfma_f32_16x16x32_f16(af[i], bf[j], acc[i][j], 0, 0, 0);
    if (s == 3) {
#pragma unroll
      for (int i = 0; i < 4; ++i)
#pragma unroll
        for (int j = 0; j < 4; ++j) {
          int col = wc * 64 + j * 16 + m16;
          int rowb = wr * 64 + i * 16 + quad * 4;
#pragma unroll
          for (int r = 0; r < 4; ++r) {
            int row = rowb + r;
            float v = (col <= row) ? acc[i][j][r] : 0.f;
            int sp = (col >> 3) ^ (row & 7);
            Ss[row * 128 + sp * 8 + (col & 7)] = (_Float16)v;
          }
          acc[i][j] = (f32x4){0.f, 0.f, 0.f, 0.f};
        }
      WAITL(0);
    }
  }

#pragma unroll
  for (int i = 0; i < 4; ++i)
#pragma unroll
    for (int j = 0; j < 4; ++j) {
      int col = wc * 64 + j * 16 + m16;
      int rowb = wr * 64 + i * 16 + quad * 4;
#pragma unroll
      for (int r = 0; r < 4; ++r)
        ath[(size_t)(tok0 + rowb + r) * DIMV + h * HD + col] = (_Float16)acc[i][j][r];
    }
}

// ---------------------------------------------------------------------------
extern "C" void kernel_launch(void* const* d_in, const int* in_sizes, int n_in,
                              void* d_out, int out_size, void* d_ws, size_t ws_size,
                              hipStream_t stream) {
  const float* x  = (const float*)d_in[0];
  const float* fc = (const float*)d_in[1];
  const float* wq = (const float*)d_in[2];
  const float* wk = (const float*)d_in[3];
  const float* wv = (const float*)d_in[4];
  const float* wo = (const float*)d_in[5];
  float* out = (float*)d_out;

  char* p = (char*)d_ws;
  _Float16* xh    = (_Float16*)p;  p += 16777216;  // 4096x2048
  _Float16* wqkvh = (_Float16*)p;  p += 16777216;  // 4096x2048 (wq|wk|wv)
  _Float16* woh   = (_Float16*)p;  p += 8388608;   // 2048x2048
  _Float16* qh    = (_Float16*)p;  p += 16777216;  // 4096x2048
  _Float16* kT    = (_Float16*)p;  p += 8388608;   // 1024x4096
  _Float16* kh    = (_Float16*)p;  p += 8388608;   // 4096x1024
  _Float16* vT    = (_Float16*)p;  p += 8388608;   // 1024x4096
  float*    kvT   = (float*)p;     p += 16777216;  // (unused; layout kept)
  _Float16* cumh  = (_Float16*)p;  p += 8388608;
  _Float16* ath   = (_Float16*)p;  p += 16777216;  // 4096x2048
  float*    fcT   = (float*)p;     p += 1048576;   // 128x2048 f32
  (void)kvT;

  // casts + fc transpose in one launch
  cast_all<<<10304, 256, 0, stream>>>(x, wq, wk, wv, wo, xh, wqkvh, woh, fc, fcT);

  // fused QKV projection + q RoPE/softmax
  hgemm_qkv_8p<<<dim3(16, 16), 512, 0, stream>>>(xh, wqkvh, fc, qh, kT, vT);

  // k rope + softmax + dual-layout write (kT in-place, kh transposed)
  k_finalize<<<128, 256, 0, stream>>>(kT, kh, fcT);

  // fused chunk-kv + exclusive cumsum -> cumh (kvT eliminated)
  kv_cum<<<64, 256, 0, stream>>>(vT, kT, cumh);

  // chunked linear attention
  attn_fused<<<512, 256, 0, stream>>>(qh, kh, cumh, vT, ath);

  // output projection
  hgemm_bt_8p<<<dim3(8, 32), 512, 0, stream>>>(ath, woh, out);
}

// Round 7
// 285.255 us; speedup vs baseline: 1.0255x; 1.0255x over previous
//
#include <hip/hip_runtime.h>
#include <math.h>

#define DIMV 2048
#define NHEAD 16
#define NKV 8
#define HD 128
#define BATCH 2
#define SEQ 2048
#define CHUNK 128
#define NCHUNK 16
#define MTOK 4096  // BATCH*SEQ
#define KVD (NKV * HD)  // 1024

typedef _Float16 half8_t __attribute__((ext_vector_type(8)));
typedef _Float16 half4_t __attribute__((ext_vector_type(4)));
typedef _Float16 half2_t __attribute__((ext_vector_type(2)));
typedef float f32x4 __attribute__((ext_vector_type(4)));

#define GLOBAL_AS __attribute__((address_space(1)))
#define LDS_AS __attribute__((address_space(3)))

#define BARX() __builtin_amdgcn_s_barrier()
#define WAITL(n) asm volatile("s_waitcnt lgkmcnt(" #n ")" ::: "memory")
#define WAITVM(n) asm volatile("s_waitcnt vmcnt(" #n ")" ::: "memory")

// ---------------------------------------------------------------------------
// All five f32->f16 casts + fc transpose in one launch. grid 10304 x 256.
// ---------------------------------------------------------------------------
__global__ __launch_bounds__(256) void cast_all(const float* __restrict__ x,
                                                const float* __restrict__ wq,
                                                const float* __restrict__ wk,
                                                const float* __restrict__ wv,
                                                const float* __restrict__ wo,
                                                _Float16* __restrict__ xh,
                                                _Float16* __restrict__ wqkvh,
                                                _Float16* __restrict__ woh,
                                                const float* __restrict__ fc,
                                                float* __restrict__ fcT) {
  __shared__ float T[64][65];
  if (blockIdx.x >= 10240) {
    int q = blockIdx.x - 10240;
    int s0 = (q & 31) * 64, d0 = (q >> 5) * 64;
    int t = threadIdx.x;
    int r = t >> 4, c4 = (t & 15) * 4;
#pragma unroll
    for (int p = 0; p < 4; ++p) {
      int sr = p * 16 + r;
      float4 v = *(const float4*)&fc[(size_t)(s0 + sr) * 128 + d0 + c4];
      T[sr][c4] = v.x; T[sr][c4 + 1] = v.y; T[sr][c4 + 2] = v.z; T[sr][c4 + 3] = v.w;
    }
    __syncthreads();
#pragma unroll
    for (int p = 0; p < 4; ++p) {
      int dr = p * 16 + r;
      float4 v = make_float4(T[c4][dr], T[c4 + 1][dr], T[c4 + 2][dr], T[c4 + 3][dr]);
      *(float4*)&fcT[(size_t)(d0 + dr) * SEQ + s0 + c4] = v;
    }
    return;
  }
  long i = (long)(blockIdx.x * 256 + threadIdx.x) * 8;
  const float* src;
  _Float16* dst;
  long off;
  if (i < 8388608)        { src = x;  dst = xh;              off = 0; }
  else if (i < 12582912)  { src = wq; dst = wqkvh;           off = 8388608; }
  else if (i < 14680064)  { src = wk; dst = wqkvh + 4194304; off = 12582912; }
  else if (i < 16777216)  { src = wv; dst = wqkvh + 6291456; off = 14680064; }
  else                    { src = wo; dst = woh;             off = 16777216; }
  long e = i - off;
  float4 a = *(const float4*)&src[e];
  float4 b = *(const float4*)&src[e + 4];
  half8_t h = {(_Float16)a.x, (_Float16)a.y, (_Float16)a.z, (_Float16)a.w,
               (_Float16)b.x, (_Float16)b.y, (_Float16)b.z, (_Float16)b.w};
  *(half8_t*)&dst[e] = h;
}

// ---------------------------------------------------------------------------
// Fused QKV projection, 256x256 tile, BK=64, 8-phase counted-vmcnt schedule.
// (Round-2 verified: ~82 us at full clock, 0 bank conflicts.)
// ---------------------------------------------------------------------------
#define STG_A(bb, kk, i, k0)                                                      \
  __builtin_amdgcn_global_load_lds(                                               \
      (const GLOBAL_AS void*)(A + aoff + (size_t)(i) * 128 * 2048 + (k0) + (kk) * 32), \
      (LDS_AS void*)(As + ((bb) * 2 + (kk)) * 8192 + (i) * 4096 + wave * 512), 16, 0, 0)
#define STG_B(bb, kk, i, k0)                                                      \
  __builtin_amdgcn_global_load_lds(                                               \
      (const GLOBAL_AS void*)(B + boff + (size_t)(i) * 128 * 2048 + (k0) + (kk) * 32), \
      (LDS_AS void*)(Bs + ((bb) * 2 + (kk)) * 8192 + (i) * 4096 + wave * 512), 16, 0, 0)

#define LDA_F(bb, kk, ih) do {                                                    \
    const _Float16* pA_ = As + ((bb) * 2 + (kk)) * 8192 +                         \
                          (wr * 128 + (ih) * 64 + m16) * 32 + pseg8;              \
    af[0] = *(const half8_t*)(pA_);                                               \
    af[1] = *(const half8_t*)(pA_ + 512);                                         \
    af[2] = *(const half8_t*)(pA_ + 1024);                                        \
    af[3] = *(const half8_t*)(pA_ + 1536);                                        \
  } while (0)
#define LDB_F(bb, kk) do {                                                        \
    const _Float16* pB_ = Bs + ((bb) * 2 + (kk)) * 8192 +                         \
                          (wc * 64 + m16) * 32 + pseg8;                           \
    bf[0] = *(const half8_t*)(pB_);                                               \
    bf[1] = *(const half8_t*)(pB_ + 512);                                         \
    bf[2] = *(const half8_t*)(pB_ + 1024);                                        \
    bf[3] = *(const half8_t*)(pB_ + 1536);                                        \
  } while (0)

#define MMX(ih) do {                                                              \
    _Pragma("unroll")                                                             \
    for (int i_ = 0; i_ < 4; ++i_)                                                \
      _Pragma("unroll")                                                           \
      for (int j_ = 0; j_ < 4; ++j_)                                              \
        acc[(ih) * 4 + i_][j_] = __builtin_amdgcn_mfma_f32_16x16x32_f16(          \
            af[i_], bf[j_], acc[(ih) * 4 + i_][j_], 0, 0, 0);                     \
  } while (0)

#define KTILE(bb, k0, DS1, DS2, DS3, DS4, VA, VB) do {                            \
  half8_t af[4], bf[4];                                                           \
  LDA_F(bb, 0, 0); LDB_F(bb, 0);                                                  \
  if (DS1) { STG_A(1 - (bb), 1, 0, (k0) + 64); STG_A(1 - (bb), 1, 1, (k0) + 64); } \
  BARX(); WAITL(0);                                                               \
  __builtin_amdgcn_s_setprio(1); MMX(0); __builtin_amdgcn_s_setprio(0);           \
  BARX();                                                                         \
  LDA_F(bb, 0, 1);                                                                \
  if (DS2) { STG_B(1 - (bb), 1, 0, (k0) + 64); STG_B(1 - (bb), 1, 1, (k0) + 64); } \
  WAITVM(VA);                                                                     \
  BARX(); WAITL(0);                                                               \
  __builtin_amdgcn_s_setprio(1); MMX(1); __builtin_amdgcn_s_setprio(0);           \
  BARX();                                                                         \
  LDA_F(bb, 1, 0); LDB_F(bb, 1);                                                  \
  if (DS3) { STG_A(bb, 0, 0, (k0) + 128); STG_A(bb, 0, 1, (k0) + 128); }          \
  BARX(); WAITL(0);                                                               \
  __builtin_amdgcn_s_setprio(1); MMX(0); __builtin_amdgcn_s_setprio(0);           \
  BARX();                                                                         \
  LDA_F(bb, 1, 1);                                                                \
  if (DS4) { STG_B(bb, 0, 0, (k0) + 128); STG_B(bb, 0, 1, (k0) + 128); }          \
  WAITVM(VB);                                                                     \
  BARX(); WAITL(0);                                                               \
  __builtin_amdgcn_s_setprio(1); MMX(1); __builtin_amdgcn_s_setprio(0);           \
  BARX();                                                                         \
} while (0)

__global__ __launch_bounds__(512, 2) void hgemm_qkv_8p(const _Float16* __restrict__ A,
                                                       const _Float16* __restrict__ B,
                                                       const float* __restrict__ fc,
                                                       _Float16* __restrict__ qh,
                                                       _Float16* __restrict__ kT,
                                                       _Float16* __restrict__ vT) {
  const int K = 2048;
  __shared__ _Float16 As[32768];  // [buf][kk][256][32]
  __shared__ _Float16 Bs[32768];
  __shared__ float qsum[4][256];

  const int tid = threadIdx.x;
  const int lane = tid & 63;
  const int wave = tid >> 6;
  const int wr = wave >> 2;
  const int wc = wave & 3;
  const int m16 = lane & 15, quad = lane >> 4;
  const int row0 = blockIdx.y * 256, col0 = blockIdx.x * 256;
  const int pseg8 = (quad ^ ((m16 >> 1) & 3)) * 8;

  const int r_ld = tid >> 2;
  const int sseg = (tid & 3) ^ ((tid >> 3) & 3);
  const size_t aoff = (size_t)(row0 + r_ld) * K + sseg * 8;
  const size_t boff = (size_t)(col0 + r_ld) * K + sseg * 8;

  f32x4 acc[8][4];
#pragma unroll
  for (int m = 0; m < 8; ++m)
#pragma unroll
    for (int j = 0; j < 4; ++j) acc[m][j] = (f32x4){0.f, 0.f, 0.f, 0.f};

  STG_A(0, 0, 0, 0); STG_A(0, 0, 1, 0); STG_B(0, 0, 0, 0); STG_B(0, 0, 1, 0);
  STG_A(0, 1, 0, 0); STG_A(0, 1, 1, 0); STG_B(0, 1, 0, 0); STG_B(0, 1, 1, 0);
  STG_A(1, 0, 0, 64); STG_A(1, 0, 1, 64); STG_B(1, 0, 0, 64); STG_B(1, 0, 1, 64);
  WAITVM(8);
  BARX();

  for (int t = 0; t < 30; t += 2) {
    KTILE(0, t * 64,      1, 1, 1, 1, 8, 8);
    KTILE(1, t * 64 + 64, 1, 1, 1, 1, 8, 8);
  }
  KTILE(0, 1920, 1, 1, 0, 0, 8, 4);
  KTILE(1, 1984, 0, 0, 0, 0, 0, 0);

  if (col0 < 2048) {
    const float sc = 0.08838834764831845f;  // 128^-0.5
    float psum[8][4];
#pragma unroll
    for (int m = 0; m < 8; ++m)
#pragma unroll
      for (int r = 0; r < 4; ++r) psum[m][r] = 0.f;
#pragma unroll
    for (int m = 0; m < 8; ++m)
#pragma unroll
      for (int j = 0; j < 4; ++j) {
        int dl2 = (wc * 64 + j * 16 + m16) & 126;
#pragma unroll
        for (int r = 0; r < 4; ++r) {
          float val = acc[m][j][r];
          float par = __shfl_xor(val, 1);
          int row_l = wr * 128 + (m >> 2) * 64 + (m & 3) * 16 + quad * 4 + r;
          int s_tok = (row0 + row_l) & (SEQ - 1);
          float2 cs = *(const float2*)&fc[(size_t)s_tok * 128 + dl2];
          float o = val * cs.x + par * ((m16 & 1) ? cs.y : -cs.y);
          float e = __expf(o * sc);
          acc[m][j][r] = e;
          psum[m][r] += e;
        }
      }
#pragma unroll
    for (int mm = 1; mm < 16; mm <<= 1)
#pragma unroll
      for (int m = 0; m < 8; ++m)
#pragma unroll
        for (int r = 0; r < 4; ++r) psum[m][r] += __shfl_xor(psum[m][r], mm);
    if (m16 == 0) {
#pragma unroll
      for (int m = 0; m < 8; ++m)
#pragma unroll
        for (int r = 0; r < 4; ++r) {
          int row_l = wr * 128 + (m >> 2) * 64 + (m & 3) * 16 + quad * 4 + r;
          qsum[wc][row_l] = psum[m][r];
        }
    }
    __syncthreads();
#pragma unroll
    for (int m = 0; m < 8; ++m)
#pragma unroll
      for (int r = 0; r < 4; ++r) {
        int row_l = wr * 128 + (m >> 2) * 64 + (m & 3) * 16 + quad * 4 + r;
        psum[m][r] = 1.f / (qsum[wc & 2][row_l] + qsum[(wc & 2) | 1][row_l]);
      }
#pragma unroll
    for (int m = 0; m < 8; ++m)
#pragma unroll
      for (int j = 0; j < 4; ++j) {
        int col = col0 + wc * 64 + j * 16 + m16;
#pragma unroll
        for (int r = 0; r < 4; ++r) {
          int row_l = wr * 128 + (m >> 2) * 64 + (m & 3) * 16 + quad * 4 + r;
          qh[(size_t)(row0 + row_l) * DIMV + col] = (_Float16)(acc[m][j][r] * psum[m][r]);
        }
      }
  } else {
#pragma unroll
    for (int m = 0; m < 8; ++m)
#pragma unroll
      for (int j = 0; j < 4; ++j) {
        int col = col0 + wc * 64 + j * 16 + m16;
        int rowb = row0 + wr * 128 + (m >> 2) * 64 + (m & 3) * 16 + quad * 4;
        half4_t hv = {(_Float16)acc[m][j][0], (_Float16)acc[m][j][1],
                      (_Float16)acc[m][j][2], (_Float16)acc[m][j][3]};
        if (col0 < 3072) {
          *(half4_t*)&kT[(size_t)(col - 2048) * MTOK + rowb] = hv;
        } else {
          *(half4_t*)&vT[(size_t)(col - 3072) * MTOK + rowb] = hv;
        }
      }
  }
}

// ---------------------------------------------------------------------------
// Output GEMM, KTILE-class schedule (round-5 verified win).
// ---------------------------------------------------------------------------
#define STGBT(bb, kk, k0) do {                                                    \
  __builtin_amdgcn_global_load_lds(                                               \
      (const GLOBAL_AS void*)(A + abase + (k0) + (kk) * 32),                      \
      (LDS_AS void*)(As + ((bb) * 2 + (kk)) * 4096 + wave * 512), 16, 0, 0);      \
  __builtin_amdgcn_global_load_lds(                                               \
      (const GLOBAL_AS void*)(B + bbase + (k0) + (kk) * 32),                      \
      (LDS_AS void*)(Bs + ((bb) * 2 + (kk)) * 8192 + wave * 512), 16, 0, 0);      \
  __builtin_amdgcn_global_load_lds(                                               \
      (const GLOBAL_AS void*)(B + bbase + (size_t)128 * 2048 + (k0) + (kk) * 32), \
      (LDS_AS void*)(Bs + ((bb) * 2 + (kk)) * 8192 + 4096 + wave * 512), 16, 0, 0);\
} while (0)

#define PHASE_BT(bb, kk, SEN, sbb, skk, sk0, VM) do {                             \
  WAITVM(VM);                                                                     \
  BARX();                                                                         \
  half8_t af[4], bf[4];                                                           \
  const _Float16* pA_ = As + ((bb) * 2 + (kk)) * 4096 +                           \
                        (wr * 64 + m16) * 32 + pseg8;                             \
  const _Float16* pB_ = Bs + ((bb) * 2 + (kk)) * 8192 +                           \
                        (wc * 64 + m16) * 32 + pseg8;                             \
  af[0] = *(const half8_t*)(pA_);        af[1] = *(const half8_t*)(pA_ + 512);    \
  af[2] = *(const half8_t*)(pA_ + 1024); af[3] = *(const half8_t*)(pA_ + 1536);   \
  bf[0] = *(const half8_t*)(pB_);        bf[1] = *(const half8_t*)(pB_ + 512);    \
  bf[2] = *(const half8_t*)(pB_ + 1024); bf[3] = *(const half8_t*)(pB_ + 1536);   \
  if (SEN) STGBT(sbb, skk, sk0);                                                  \
  WAITL(0);                                                                       \
  __builtin_amdgcn_s_setprio(1);                                                  \
  _Pragma("unroll")                                                               \
  for (int i_ = 0; i_ < 4; ++i_)                                                  \
    _Pragma("unroll")                                                             \
    for (int j_ = 0; j_ < 4; ++j_)                                                \
      acc[i_][j_] = __builtin_amdgcn_mfma_f32_16x16x32_f16(                       \
          af[i_], bf[j_], acc[i_][j_], 0, 0, 0);                                  \
  __builtin_amdgcn_s_setprio(0);                                                  \
} while (0)

__global__ __launch_bounds__(512, 2) void hgemm_bt_8p(const _Float16* __restrict__ A,
                                                      const _Float16* __restrict__ B,
                                                      float* __restrict__ C) {
  const int K = 2048, N = 2048;
  __shared__ _Float16 As[16384];  // [buf][kk][128][32]
  __shared__ _Float16 Bs[32768];  // [buf][kk][256][32]

  const int tid = threadIdx.x;
  const int lane = tid & 63;
  const int wave = tid >> 6;
  const int wr = wave >> 2;
  const int wc = wave & 3;
  const int m16 = lane & 15, quad = lane >> 4;
  const int row0 = blockIdx.y * 128, col0 = blockIdx.x * 256;
  const int pseg8 = (quad ^ ((m16 >> 1) & 3)) * 8;

  const int r_ld = tid >> 2;
  const int sseg = (tid & 3) ^ ((tid >> 3) & 3);
  const size_t abase = (size_t)(row0 + r_ld) * K + sseg * 8;
  const size_t bbase = (size_t)(col0 + r_ld) * K + sseg * 8;

  f32x4 acc[4][4];
#pragma unroll
  for (int i = 0; i < 4; ++i)
#pragma unroll
    for (int j = 0; j < 4; ++j) acc[i][j] = (f32x4){0.f, 0.f, 0.f, 0.f};

  STGBT(0, 0, 0); STGBT(0, 1, 0); STGBT(1, 0, 64);

  for (int t = 0; t < 30; ++t) {
    const int bb = t & 1;
    const int k0 = t * 64;
    PHASE_BT(bb, 0, 1, bb ^ 1, 1, k0 + 64, 6);
    PHASE_BT(bb, 1, 1, bb, 0, k0 + 128, 6);
  }
  PHASE_BT(0, 0, 1, 1, 1, 1984, 6);
  PHASE_BT(0, 1, 0, 0, 0, 0, 6);
  PHASE_BT(1, 0, 0, 0, 0, 0, 3);
  PHASE_BT(1, 1, 0, 0, 0, 0, 0);

#pragma unroll
  for (int i = 0; i < 4; ++i)
#pragma unroll
    for (int j = 0; j < 4; ++j) {
      int col = col0 + wc * 64 + j * 16 + m16;
      int rowb = row0 + wr * 64 + i * 16 + quad * 4;
#pragma unroll
      for (int r = 0; r < 4; ++r) C[(size_t)(rowb + r) * N + col] = acc[i][j][r];
    }
}

// ---------------------------------------------------------------------------
// RoPE + token-softmax on kT [1024 dims][4096 tokens] fp16, in place.
// (Round-5 version: 1024 blocks, full parallelism.)
// ---------------------------------------------------------------------------
__global__ __launch_bounds__(256) void k_rope_softmax_T(_Float16* __restrict__ kT,
                                                        const float* __restrict__ fcT) {
  int bi = blockIdx.x;
  int b = bi & 1, pr = bi >> 1;
  int d0 = pr * 2, dl = d0 & 127;
  int t = threadIdx.x;
  size_t r0 = (size_t)d0 * MTOK + b * SEQ + t * 8;
  size_t r1 = r0 + MTOK;
  half8_t x0v = *(half8_t*)&kT[r0];
  half8_t x1v = *(half8_t*)&kT[r1];
  int s8 = t * 8;
  float4 ca = *(const float4*)&fcT[(size_t)dl * SEQ + s8];
  float4 cb = *(const float4*)&fcT[(size_t)dl * SEQ + s8 + 4];
  float4 sa = *(const float4*)&fcT[(size_t)(dl + 1) * SEQ + s8];
  float4 sb = *(const float4*)&fcT[(size_t)(dl + 1) * SEQ + s8 + 4];
  float cc[8] = {ca.x, ca.y, ca.z, ca.w, cb.x, cb.y, cb.z, cb.w};
  float ss[8] = {sa.x, sa.y, sa.z, sa.w, sb.x, sb.y, sb.z, sb.w};
  float e0[8], e1[8];
  float sum0 = 0.f, sum1 = 0.f;
#pragma unroll
  for (int j = 0; j < 8; ++j) {
    float x0 = (float)x0v[j], x1 = (float)x1v[j];
    float o0 = x0 * cc[j] - x1 * ss[j];
    float o1 = x0 * ss[j] + x1 * cc[j];
    e0[j] = expf(o0); e1[j] = expf(o1);
    sum0 += e0[j]; sum1 += e1[j];
  }
#pragma unroll
  for (int off = 1; off < 64; off <<= 1) {
    sum0 += __shfl_xor(sum0, off);
    sum1 += __shfl_xor(sum1, off);
  }
  __shared__ float red[8];
  if ((t & 63) == 0) { red[(t >> 6) * 2] = sum0; red[(t >> 6) * 2 + 1] = sum1; }
  __syncthreads();
  float S0 = red[0] + red[2] + red[4] + red[6];
  float S1 = red[1] + red[3] + red[5] + red[7];
  float i0 = 1.f / S0, i1 = 1.f / S1;
  half8_t w0, w1;
#pragma unroll
  for (int j = 0; j < 8; ++j) {
    w0[j] = (_Float16)(e0[j] * i0);
    w1[j] = (_Float16)(e1[j] * i1);
  }
  *(half8_t*)&kT[r0] = w0;
  *(half8_t*)&kT[r1] = w1;
}

// ---------------------------------------------------------------------------
// kT [1024][4096] -> kh [4096][1024]  (fp16 tile transpose)
// ---------------------------------------------------------------------------
__global__ __launch_bounds__(256) void transpose_k(const _Float16* __restrict__ kT,
                                                   _Float16* __restrict__ kh) {
  __shared__ _Float16 T[64][65];
  int t0 = blockIdx.x * 64, d0 = blockIdx.y * 64;
  int t = threadIdx.x;
  int r = t >> 3, c8 = (t & 7) * 8;
#pragma unroll
  for (int p = 0; p < 2; ++p) {
    int dr = p * 32 + r;
    half8_t v = *(const half8_t*)&kT[(size_t)(d0 + dr) * MTOK + t0 + c8];
#pragma unroll
    for (int j = 0; j < 8; ++j) T[c8 + j][dr] = v[j];
  }
  __syncthreads();
#pragma unroll
  for (int p = 0; p < 2; ++p) {
    int tr = p * 32 + r;
    half8_t v;
#pragma unroll
    for (int j = 0; j < 8; ++j) v[j] = T[tr][c8 + j];
    *(half8_t*)&kh[(size_t)(t0 + tr) * KVD + d0 + c8] = v;
  }
}

// ---------------------------------------------------------------------------
// kvT[e][d] = sum_c v[c,e]*k[c,d] per (b,kvh,chunk). MFMA fp16, M=N=K=128.
// (Round-5 version: 256 blocks, double-buffered staging.)
// ---------------------------------------------------------------------------
__global__ __launch_bounds__(256) void kv_chunk_mfma(const _Float16* __restrict__ vT,
                                                     const _Float16* __restrict__ kT,
                                                     float* __restrict__ kvT) {
  __shared__ _Float16 As[2][128 * 32];
  __shared__ _Float16 Bs[2][128 * 32];
  int bi = blockIdx.x;
  int n = bi & 15, kvh = (bi >> 4) & 7, b = bi >> 7;
  int tok0 = b * SEQ + n * CHUNK;
  const int tid = threadIdx.x;
  const int lane = tid & 63;
  const int wave = tid >> 6;
  const int wr = wave & 1, wc = wave >> 1;
  const int m16 = lane & 15, quad = lane >> 4;
  const int qsw8 = (quad ^ ((m16 >> 1) & 3)) * 8;

  f32x4 acc[4][4];
#pragma unroll
  for (int i = 0; i < 4; ++i)
#pragma unroll
    for (int j = 0; j < 4; ++j) acc[i][j] = (f32x4){0.f, 0.f, 0.f, 0.f};

  const int r_ld = tid >> 2;
  const int sseg = (tid & 3) ^ ((tid >> 3) & 3);
  const size_t a_base = (size_t)(kvh * HD + r_ld) * MTOK + tok0 + sseg * 8;

#pragma unroll
  for (int i = 0; i < 2; ++i) {
    __builtin_amdgcn_global_load_lds(
        (const GLOBAL_AS void*)(vT + a_base + (size_t)i * 64 * MTOK),
        (LDS_AS void*)(&As[0][0] + i * 2048 + wave * 512), 16, 0, 0);
    __builtin_amdgcn_global_load_lds(
        (const GLOBAL_AS void*)(kT + a_base + (size_t)i * 64 * MTOK),
        (LDS_AS void*)(&Bs[0][0] + i * 2048 + wave * 512), 16, 0, 0);
  }

#pragma unroll
  for (int s = 0; s < 4; ++s) {
    WAITVM(0);
    BARX();
    if (s < 3) {
      const int k0 = (s + 1) * 32;
      const int bb = (s + 1) & 1;
#pragma unroll
      for (int i = 0; i < 2; ++i) {
        __builtin_amdgcn_global_load_lds(
            (const GLOBAL_AS void*)(vT + a_base + (size_t)i * 64 * MTOK + k0),
            (LDS_AS void*)(&As[bb][0] + i * 2048 + wave * 512), 16, 0, 0);
        __builtin_amdgcn_global_load_lds(
            (const GLOBAL_AS void*)(kT + a_base + (size_t)i * 64 * MTOK + k0),
            (LDS_AS void*)(&Bs[bb][0] + i * 2048 + wave * 512), 16, 0, 0);
      }
    }
    const _Float16* ra = &As[s & 1][0];
    const _Float16* rb = &Bs[s & 1][0];
    half8_t af[4], bf[4];
#pragma unroll
    for (int i = 0; i < 4; ++i) {
      af[i] = *(const half8_t*)&ra[(wr * 64 + i * 16 + m16) * 32 + qsw8];
      bf[i] = *(const half8_t*)&rb[(wc * 64 + i * 16 + m16) * 32 + qsw8];
    }
#pragma unroll
    for (int i = 0; i < 4; ++i)
#pragma unroll
      for (int j = 0; j < 4; ++j)
        acc[i][j] = __builtin_amdgcn_mfma_f32_16x16x32_f16(af[i], bf[j], acc[i][j], 0, 0, 0);
  }
#pragma unroll
  for (int i = 0; i < 4; ++i)
#pragma unroll
    for (int j = 0; j < 4; ++j) {
      int col = wc * 64 + j * 16 + m16;
      int rowb = wr * 64 + i * 16 + quad * 4;
#pragma unroll
      for (int r = 0; r < 4; ++r)
        kvT[(size_t)bi * 16384 + (size_t)(rowb + r) * 128 + col] = acc[i][j][r];
    }
}

// ---------------------------------------------------------------------------
// Exclusive chunk-cumsum of kvT (f32), emitting fp16 cumT. grid 1024x256.
// ---------------------------------------------------------------------------
__global__ __launch_bounds__(256) void cumsum_h(const float* __restrict__ kvT,
                                                _Float16* __restrict__ cumh) {
  int gid = blockIdx.x * 256 + threadIdx.x;
  int bk = gid >> 14, idx = gid & 16383;
  size_t base = (size_t)bk * NCHUNK * 16384 + idx;
  float run = 0.f;
#pragma unroll
  for (int n = 0; n < NCHUNK; ++n) {
    cumh[base + (size_t)n * 16384] = (_Float16)run;
    run += kvT[base + (size_t)n * 16384];
  }
}

// ---------------------------------------------------------------------------
// Fused scores+output per (b,h,chunk). v3: 8 uniform steps.
//  Steps 0-3 (dual): accs += q@k^T slice, acc += q@cum slice (SHARED af!)
//    with kh and cumh tiles double-buffered in Bk/Bc.
//  Step 3 end: barrier; tril(accs) -> Ss ALIASED onto Qs (q dead after s=3).
//  Steps 4-7: acc += S@v (vT tiles double-buffered in Bk).
//  LDS 64 KB (Qs/Ss shared 32K + Bk 16K + Bc 16K) -> 2 blocks/CU.
// ---------------------------------------------------------------------------
__global__ __launch_bounds__(256) void attn_fused(const _Float16* __restrict__ qh,
                                                  const _Float16* __restrict__ kh,
                                                  const _Float16* __restrict__ cumh,
                                                  const _Float16* __restrict__ vT,
                                                  _Float16* __restrict__ ath) {
  __shared__ _Float16 QS[128 * 128];   // Qs for steps 0-3, then Ss for 4-7
  __shared__ _Float16 Bk[2][128 * 32];
  __shared__ _Float16 Bc[2][128 * 32];
  int bi = blockIdx.x;
  int n = bi & 15, h = (bi >> 4) & 15, b = bi >> 8;
  int kvh = h >> 1;
  int tok0 = b * SEQ + n * CHUNK;
  const int tid = threadIdx.x;
  const int lane = tid & 63;
  const int wave = tid >> 6;
  const int wr = wave & 1, wc = wave >> 1;
  const int m16 = lane & 15, quad = lane >> 4;
  const int qsw8 = (quad ^ ((m16 >> 1) & 3)) * 8;
  const int r_ld = tid >> 2;
  const int sseg = (tid & 3) ^ ((tid >> 3) & 3);

  f32x4 acc[4][4];   // output accumulator (inter + intra)
  f32x4 accs[4][4];  // scores accumulator
#pragma unroll
  for (int i = 0; i < 4; ++i)
#pragma unroll
    for (int j = 0; j < 4; ++j) {
      acc[i][j] = (f32x4){0.f, 0.f, 0.f, 0.f};
      accs[i][j] = (f32x4){0.f, 0.f, 0.f, 0.f};
    }

  // ---- stage Q once (8 rounds x 16 rows); source col pre-swizzled ----
  const int qrow = tid >> 4;
  const int qsl = (tid & 15) ^ (qrow & 7);
  const size_t qsrc = (size_t)(tok0 + qrow) * DIMV + h * HD + qsl * 8;
#pragma unroll
  for (int p = 0; p < 8; ++p)
    __builtin_amdgcn_global_load_lds(
        (const GLOBAL_AS void*)(qh + qsrc + (size_t)p * 16 * DIMV),
        (LDS_AS void*)(QS + p * 2048 + wave * 512), 16, 0, 0);

  const size_t kbase = (size_t)(tok0 + r_ld) * KVD + kvh * HD + sseg * 8;
  const size_t cbase = ((size_t)((b * 8 + kvh) * 16 + n)) * 16384 + (size_t)r_ld * 128 + sseg * 8;
  const size_t vbase = (size_t)(kvh * HD + r_ld) * MTOK + tok0 + sseg * 8;

  // stage step-0 tiles: kh k0=0 -> Bk[0], cumh k0=0 -> Bc[0]
#pragma unroll
  for (int i = 0; i < 2; ++i) {
    __builtin_amdgcn_global_load_lds(
        (const GLOBAL_AS void*)(kh + kbase + (size_t)i * 64 * KVD),
        (LDS_AS void*)(&Bk[0][0] + i * 2048 + wave * 512), 16, 0, 0);
    __builtin_amdgcn_global_load_lds(
        (const GLOBAL_AS void*)(cumh + cbase + (size_t)i * 64 * 128),
        (LDS_AS void*)(&Bc[0][0] + i * 2048 + wave * 512), 16, 0, 0);
  }

#pragma unroll
  for (int s = 0; s < 8; ++s) {
    WAITVM(0);
    BARX();
    // stage next-step tiles
    if (s < 3) {
      const int k0 = (s + 1) * 32;
      const int bb = (s + 1) & 1;
#pragma unroll
      for (int i = 0; i < 2; ++i) {
        __builtin_amdgcn_global_load_lds(
            (const GLOBAL_AS void*)(kh + kbase + (size_t)i * 64 * KVD + k0),
            (LDS_AS void*)(&Bk[bb][0] + i * 2048 + wave * 512), 16, 0, 0);
        __builtin_amdgcn_global_load_lds(
            (const GLOBAL_AS void*)(cumh + cbase + (size_t)i * 64 * 128 + k0),
            (LDS_AS void*)(&Bc[bb][0] + i * 2048 + wave * 512), 16, 0, 0);
      }
    } else if (s < 7) {
      const int k0 = (s - 3) * 32;   // vT slice for step s+1
      const int bb = (s + 1) & 1;
#pragma unroll
      for (int i = 0; i < 2; ++i)
        __builtin_amdgcn_global_load_lds(
            (const GLOBAL_AS void*)(vT + vbase + (size_t)i * 64 * MTOK + k0),
            (LDS_AS void*)(&Bk[bb][0] + i * 2048 + wave * 512), 16, 0, 0);
    }
    if (s < 4) {
      // dual MFMA: af (q slice) shared between k^T and cum products
      half8_t af[4], bfk[4], bfc[4];
      const int sl4 = s * 4;
      const _Float16* rk = &Bk[s & 1][0];
      const _Float16* rc = &Bc[s & 1][0];
#pragma unroll
      for (int i = 0; i < 4; ++i) {
        int row = wr * 64 + i * 16 + m16;
        af[i] = *(const half8_t*)&QS[row * 128 + ((sl4 + quad) ^ (m16 & 7)) * 8];
        bfk[i] = *(const half8_t*)&rk[(wc * 64 + i * 16 + m16) * 32 + qsw8];
        bfc[i] = *(const half8_t*)&rc[(wc * 64 + i * 16 + m16) * 32 + qsw8];
      }
#pragma unroll
      for (int i = 0; i < 4; ++i)
#pragma unroll
        for (int j = 0; j < 4; ++j) {
          accs[i][j] = __builtin_amdgcn_mfma_f32_16x16x32_f16(af[i], bfk[j], accs[i][j], 0, 0, 0);
          acc[i][j] = __builtin_amdgcn_mfma_f32_16x16x32_f16(af[i], bfc[j], acc[i][j], 0, 0, 0);
        }
      if (s == 3) {
        BARX();  // all waves done reading QS (q) before aliasing it with Ss
#pragma unroll
        for (int i = 0; i < 4; ++i)
#pragma unroll
          for (int j = 0; j < 4; ++j) {
            int col = wc * 64 + j * 16 + m16;
            int rowb = wr * 64 + i * 16 + quad * 4;
#pragma unroll
            for (int r = 0; r < 4; ++r) {
              int row = rowb + r;
              float v = (col <= row) ? accs[i][j][r] : 0.f;
              int sp = (col >> 3) ^ (row & 7);
              QS[row * 128 + sp * 8 + (col & 7)] = (_Float16)v;
            }
          }
        WAITL(0);  // drain Ss writes before next step's barrier publishes them
      }
    } else {
      half8_t af[4], bf[4];
      const int sl4 = (s - 4) * 4;
      const _Float16* rk = &Bk[s & 1][0];
#pragma unroll
      for (int i = 0; i < 4; ++i) {
        int row = wr * 64 + i * 16 + m16;
        af[i] = *(const half8_t*)&QS[row * 128 + ((sl4 + quad) ^ (m16 & 7)) * 8];
        bf[i] = *(const half8_t*)&rk[(wc * 64 + i * 16 + m16) * 32 + qsw8];
      }
#pragma unroll
      for (int i = 0; i < 4; ++i)
#pragma unroll
        for (int j = 0; j < 4; ++j)
          acc[i][j] = __builtin_amdgcn_mfma_f32_16x16x32_f16(af[i], bf[j], acc[i][j], 0, 0, 0);
    }
  }

#pragma unroll
  for (int i = 0; i < 4; ++i)
#pragma unroll
    for (int j = 0; j < 4; ++j) {
      int col = wc * 64 + j * 16 + m16;
      int rowb = wr * 64 + i * 16 + quad * 4;
#pragma unroll
      for (int r = 0; r < 4; ++r)
        ath[(size_t)(tok0 + rowb + r) * DIMV + h * HD + col] = (_Float16)acc[i][j][r];
    }
}

// ---------------------------------------------------------------------------
extern "C" void kernel_launch(void* const* d_in, const int* in_sizes, int n_in,
                              void* d_out, int out_size, void* d_ws, size_t ws_size,
                              hipStream_t stream) {
  const float* x  = (const float*)d_in[0];
  const float* fc = (const float*)d_in[1];
  const float* wq = (const float*)d_in[2];
  const float* wk = (const float*)d_in[3];
  const float* wv = (const float*)d_in[4];
  const float* wo = (const float*)d_in[5];
  float* out = (float*)d_out;

  char* p = (char*)d_ws;
  _Float16* xh    = (_Float16*)p;  p += 16777216;  // 4096x2048
  _Float16* wqkvh = (_Float16*)p;  p += 16777216;  // 4096x2048 (wq|wk|wv)
  _Float16* woh   = (_Float16*)p;  p += 8388608;   // 2048x2048
  _Float16* qh    = (_Float16*)p;  p += 16777216;  // 4096x2048
  _Float16* kT    = (_Float16*)p;  p += 8388608;   // 1024x4096
  _Float16* kh    = (_Float16*)p;  p += 8388608;   // 4096x1024
  _Float16* vT    = (_Float16*)p;  p += 8388608;   // 1024x4096
  float*    kvT   = (float*)p;     p += 16777216;  // 256x128x128 f32
  _Float16* cumh  = (_Float16*)p;  p += 8388608;
  _Float16* ath   = (_Float16*)p;  p += 16777216;  // 4096x2048
  float*    fcT   = (float*)p;     p += 1048576;   // 128x2048 f32

  // casts + fc transpose in one launch
  cast_all<<<10304, 256, 0, stream>>>(x, wq, wk, wv, wo, xh, wqkvh, woh, fc, fcT);

  // fused QKV projection + q RoPE/softmax
  hgemm_qkv_8p<<<dim3(16, 16), 512, 0, stream>>>(xh, wqkvh, fc, qh, kT, vT);

  // k rope + softmax, then transpose to token-major (R5 high-parallelism pair)
  k_rope_softmax_T<<<1024, 256, 0, stream>>>(kT, fcT);
  transpose_k<<<dim3(64, 16), 256, 0, stream>>>(kT, kh);

  // chunked linear attention (R5 pair)
  kv_chunk_mfma<<<256, 256, 0, stream>>>(vT, kT, kvT);
  cumsum_h<<<1024, 256, 0, stream>>>(kvT, cumh);

  // fused attention core (v3: 8 steps, dual-B, Qs/Ss aliased)
  attn_fused<<<512, 256, 0, stream>>>(qh, kh, cumh, vT, ath);

  // output projection
  hgemm_bt_8p<<<dim3(8, 32), 512, 0, stream>>>(ath, woh, out);
}

// Round 8
// 282.997 us; speedup vs baseline: 1.0337x; 1.0080x over previous
//
#include <hip/hip_runtime.h>
#include <math.h>

#define DIMV 2048
#define NHEAD 16
#define NKV 8
#define HD 128
#define BATCH 2
#define SEQ 2048
#define CHUNK 128
#define NCHUNK 16
#define MTOK 4096  // BATCH*SEQ
#define KVD (NKV * HD)  // 1024

typedef _Float16 half8_t __attribute__((ext_vector_type(8)));
typedef _Float16 half4_t __attribute__((ext_vector_type(4)));
typedef _Float16 half2_t __attribute__((ext_vector_type(2)));
typedef float f32x4 __attribute__((ext_vector_type(4)));

#define GLOBAL_AS __attribute__((address_space(1)))
#define LDS_AS __attribute__((address_space(3)))

#define BARX() __builtin_amdgcn_s_barrier()
#define WAITL(n) asm volatile("s_waitcnt lgkmcnt(" #n ")" ::: "memory")
#define WAITVM(n) asm volatile("s_waitcnt vmcnt(" #n ")" ::: "memory")

// ---------------------------------------------------------------------------
// All five f32->f16 casts + fc transpose in one launch. grid 10304 x 256.
// ---------------------------------------------------------------------------
__global__ __launch_bounds__(256) void cast_all(const float* __restrict__ x,
                                                const float* __restrict__ wq,
                                                const float* __restrict__ wk,
                                                const float* __restrict__ wv,
                                                const float* __restrict__ wo,
                                                _Float16* __restrict__ xh,
                                                _Float16* __restrict__ wqkvh,
                                                _Float16* __restrict__ woh,
                                                const float* __restrict__ fc,
                                                float* __restrict__ fcT) {
  __shared__ float T[64][65];
  if (blockIdx.x >= 10240) {
    int q = blockIdx.x - 10240;
    int s0 = (q & 31) * 64, d0 = (q >> 5) * 64;
    int t = threadIdx.x;
    int r = t >> 4, c4 = (t & 15) * 4;
#pragma unroll
    for (int p = 0; p < 4; ++p) {
      int sr = p * 16 + r;
      float4 v = *(const float4*)&fc[(size_t)(s0 + sr) * 128 + d0 + c4];
      T[sr][c4] = v.x; T[sr][c4 + 1] = v.y; T[sr][c4 + 2] = v.z; T[sr][c4 + 3] = v.w;
    }
    __syncthreads();
#pragma unroll
    for (int p = 0; p < 4; ++p) {
      int dr = p * 16 + r;
      float4 v = make_float4(T[c4][dr], T[c4 + 1][dr], T[c4 + 2][dr], T[c4 + 3][dr]);
      *(float4*)&fcT[(size_t)(d0 + dr) * SEQ + s0 + c4] = v;
    }
    return;
  }
  long i = (long)(blockIdx.x * 256 + threadIdx.x) * 8;
  const float* src;
  _Float16* dst;
  long off;
  if (i < 8388608)        { src = x;  dst = xh;              off = 0; }
  else if (i < 12582912)  { src = wq; dst = wqkvh;           off = 8388608; }
  else if (i < 14680064)  { src = wk; dst = wqkvh + 4194304; off = 12582912; }
  else if (i < 16777216)  { src = wv; dst = wqkvh + 6291456; off = 14680064; }
  else                    { src = wo; dst = woh;             off = 16777216; }
  long e = i - off;
  float4 a = *(const float4*)&src[e];
  float4 b = *(const float4*)&src[e + 4];
  half8_t h = {(_Float16)a.x, (_Float16)a.y, (_Float16)a.z, (_Float16)a.w,
               (_Float16)b.x, (_Float16)b.y, (_Float16)b.z, (_Float16)b.w};
  *(half8_t*)&dst[e] = h;
}

// ---------------------------------------------------------------------------
// Fused QKV projection, 256x256 tile, BK=64. v2: TWO phases per K-tile
// (32-MFMA clusters) instead of four 16-MFMA phases -- halves the per-phase
// fixed cost (2 barriers + lgkmcnt(0) drain) per unit of MFMA work.
// Per phase: 12 ds_read_b128 (8 A rows + 4 B) + 4 global_load_lds staging +
// counted vmcnt(8) + barrier + lgkm(0) + setprio + 32 MFMA + barrier.
// Ledger: steady-state 12 outstanding at each wait, oldest 4 must land ->
// vmcnt(8); tail 8 -> 4 -> 0 -> 0. Swizzle unchanged (0 conflicts verified).
// grid dim3(16,16) x 512 threads.
// ---------------------------------------------------------------------------
#define STG_A(bb, kk, i, k0)                                                      \
  __builtin_amdgcn_global_load_lds(                                               \
      (const GLOBAL_AS void*)(A + aoff + (size_t)(i) * 128 * 2048 + (k0) + (kk) * 32), \
      (LDS_AS void*)(As + ((bb) * 2 + (kk)) * 8192 + (i) * 4096 + wave * 512), 16, 0, 0)
#define STG_B(bb, kk, i, k0)                                                      \
  __builtin_amdgcn_global_load_lds(                                               \
      (const GLOBAL_AS void*)(B + boff + (size_t)(i) * 128 * 2048 + (k0) + (kk) * 32), \
      (LDS_AS void*)(Bs + ((bb) * 2 + (kk)) * 8192 + (i) * 4096 + wave * 512), 16, 0, 0)

// One phase: consume (bb,kk); optionally stage 4 loads into (sbb,skk) at sk0.
#define KT2(bb, kk, SEN, sbb, skk, sk0, VM) do {                                  \
  half8_t af[8], bf[4];                                                           \
  const _Float16* pA_ = As + ((bb) * 2 + (kk)) * 8192 +                           \
                        (wr * 128 + m16) * 32 + pseg8;                            \
  const _Float16* pB_ = Bs + ((bb) * 2 + (kk)) * 8192 +                           \
                        (wc * 64 + m16) * 32 + pseg8;                             \
  _Pragma("unroll")                                                               \
  for (int m_ = 0; m_ < 8; ++m_) af[m_] = *(const half8_t*)(pA_ + m_ * 512);      \
  _Pragma("unroll")                                                               \
  for (int j_ = 0; j_ < 4; ++j_) bf[j_] = *(const half8_t*)(pB_ + j_ * 512);      \
  if (SEN) {                                                                      \
    STG_A(sbb, skk, 0, sk0); STG_A(sbb, skk, 1, sk0);                             \
    STG_B(sbb, skk, 0, sk0); STG_B(sbb, skk, 1, sk0);                             \
  }                                                                               \
  WAITVM(VM);                                                                     \
  BARX(); WAITL(0);                                                               \
  __builtin_amdgcn_s_setprio(1);                                                  \
  _Pragma("unroll")                                                               \
  for (int m_ = 0; m_ < 8; ++m_)                                                  \
    _Pragma("unroll")                                                             \
    for (int j_ = 0; j_ < 4; ++j_)                                                \
      acc[m_][j_] = __builtin_amdgcn_mfma_f32_16x16x32_f16(                       \
          af[m_], bf[j_], acc[m_][j_], 0, 0, 0);                                  \
  __builtin_amdgcn_s_setprio(0);                                                  \
  BARX();                                                                         \
} while (0)

__global__ __launch_bounds__(512, 2) void hgemm_qkv_8p(const _Float16* __restrict__ A,
                                                       const _Float16* __restrict__ B,
                                                       const float* __restrict__ fc,
                                                       _Float16* __restrict__ qh,
                                                       _Float16* __restrict__ kT,
                                                       _Float16* __restrict__ vT) {
  const int K = 2048;
  __shared__ _Float16 As[32768];  // [buf][kk][256][32]
  __shared__ _Float16 Bs[32768];
  __shared__ float qsum[4][256];

  const int tid = threadIdx.x;
  const int lane = tid & 63;
  const int wave = tid >> 6;
  const int wr = wave >> 2;   // 0..1 : 128-row half
  const int wc = wave & 3;    // 0..3 : 64-col quarter
  const int m16 = lane & 15, quad = lane >> 4;
  const int row0 = blockIdx.y * 256, col0 = blockIdx.x * 256;
  // read-side seg: keyed on (row>>1)&3 = (m16>>1)&3  (64B rows)
  const int pseg8 = (quad ^ ((m16 >> 1) & 3)) * 8;

  // staging address (source pre-swizzled with the same (row>>1)&3 key)
  const int r_ld = tid >> 2;                  // 0..127
  const int sseg = (tid & 3) ^ ((tid >> 3) & 3);
  const size_t aoff = (size_t)(row0 + r_ld) * K + sseg * 8;
  const size_t boff = (size_t)(col0 + r_ld) * K + sseg * 8;

  f32x4 acc[8][4];
#pragma unroll
  for (int m = 0; m < 8; ++m)
#pragma unroll
    for (int j = 0; j < 4; ++j) acc[m][j] = (f32x4){0.f, 0.f, 0.f, 0.f};

  // prologue: kk0(0), kk1(0), kk0(1)  (12 loads)
  STG_A(0, 0, 0, 0); STG_A(0, 0, 1, 0); STG_B(0, 0, 0, 0); STG_B(0, 0, 1, 0);
  STG_A(0, 1, 0, 0); STG_A(0, 1, 1, 0); STG_B(0, 1, 0, 0); STG_B(0, 1, 1, 0);
  STG_A(1, 0, 0, 64); STG_A(1, 0, 1, 64); STG_B(1, 0, 0, 64); STG_B(1, 0, 1, 64);
  WAITVM(8);  // kk0(0) landed; kk1(0)+kk0(1) stay in flight
  BARX();

  for (int t = 0; t < 30; ++t) {
    const int bb = t & 1;
    const int k0 = t * 64;
    KT2(bb, 0, 1, bb ^ 1, 1, k0 + 64, 8);   // consume kk0(t); stage kk1(t+1)
    KT2(bb, 1, 1, bb, 0, k0 + 128, 8);      // consume kk1(t); stage kk0(t+2)
  }
  KT2(0, 0, 1, 1, 1, 1984, 8);  // t=30 PH1: stage kk1(31)
  KT2(0, 1, 0, 0, 0, 0, 4);     // t=30 PH2: kk0(31) must land
  KT2(1, 0, 0, 0, 0, 0, 0);     // t=31 PH1: kk1(31) must land
  KT2(1, 1, 0, 0, 0, 0, 0);     // t=31 PH2: drain

  // ---- epilogue ----
  // row_l(m,r) = wr*128 + m*16 + quad*4 + r ; col_l(j) = wc*64 + j*16 + m16
  if (col0 < 2048) {
    const float sc = 0.08838834764831845f;  // 128^-0.5
    float psum[8][4];
#pragma unroll
    for (int m = 0; m < 8; ++m)
#pragma unroll
      for (int r = 0; r < 4; ++r) psum[m][r] = 0.f;
#pragma unroll
    for (int m = 0; m < 8; ++m)
#pragma unroll
      for (int j = 0; j < 4; ++j) {
        int dl2 = (wc * 64 + j * 16 + m16) & 126;
#pragma unroll
        for (int r = 0; r < 4; ++r) {
          float val = acc[m][j][r];
          float par = __shfl_xor(val, 1);
          int row_l = wr * 128 + m * 16 + quad * 4 + r;
          int s_tok = (row0 + row_l) & (SEQ - 1);
          float2 cs = *(const float2*)&fc[(size_t)s_tok * 128 + dl2];
          float o = val * cs.x + par * ((m16 & 1) ? cs.y : -cs.y);
          float e = __expf(o * sc);
          acc[m][j][r] = e;
          psum[m][r] += e;
        }
      }
#pragma unroll
    for (int mm = 1; mm < 16; mm <<= 1)
#pragma unroll
      for (int m = 0; m < 8; ++m)
#pragma unroll
        for (int r = 0; r < 4; ++r) psum[m][r] += __shfl_xor(psum[m][r], mm);
    if (m16 == 0) {
#pragma unroll
      for (int m = 0; m < 8; ++m)
#pragma unroll
        for (int r = 0; r < 4; ++r) {
          int row_l = wr * 128 + m * 16 + quad * 4 + r;
          qsum[wc][row_l] = psum[m][r];
        }
    }
    __syncthreads();
#pragma unroll
    for (int m = 0; m < 8; ++m)
#pragma unroll
      for (int r = 0; r < 4; ++r) {
        int row_l = wr * 128 + m * 16 + quad * 4 + r;
        psum[m][r] = 1.f / (qsum[wc & 2][row_l] + qsum[(wc & 2) | 1][row_l]);
      }
#pragma unroll
    for (int m = 0; m < 8; ++m)
#pragma unroll
      for (int j = 0; j < 4; ++j) {
        int col = col0 + wc * 64 + j * 16 + m16;
#pragma unroll
        for (int r = 0; r < 4; ++r) {
          int row_l = wr * 128 + m * 16 + quad * 4 + r;
          qh[(size_t)(row0 + row_l) * DIMV + col] = (_Float16)(acc[m][j][r] * psum[m][r]);
        }
      }
  } else {
#pragma unroll
    for (int m = 0; m < 8; ++m)
#pragma unroll
      for (int j = 0; j < 4; ++j) {
        int col = col0 + wc * 64 + j * 16 + m16;
        int rowb = row0 + wr * 128 + m * 16 + quad * 4;
        half4_t hv = {(_Float16)acc[m][j][0], (_Float16)acc[m][j][1],
                      (_Float16)acc[m][j][2], (_Float16)acc[m][j][3]};
        if (col0 < 3072) {
          *(half4_t*)&kT[(size_t)(col - 2048) * MTOK + rowb] = hv;
        } else {
          *(half4_t*)&vT[(size_t)(col - 3072) * MTOK + rowb] = hv;
        }
      }
  }
}

// ---------------------------------------------------------------------------
// Output GEMM, KTILE-class schedule (round-5 verified win).
// ---------------------------------------------------------------------------
#define STGBT(bb, kk, k0) do {                                                    \
  __builtin_amdgcn_global_load_lds(                                               \
      (const GLOBAL_AS void*)(A + abase + (k0) + (kk) * 32),                      \
      (LDS_AS void*)(As + ((bb) * 2 + (kk)) * 4096 + wave * 512), 16, 0, 0);      \
  __builtin_amdgcn_global_load_lds(                                               \
      (const GLOBAL_AS void*)(B + bbase + (k0) + (kk) * 32),                      \
      (LDS_AS void*)(Bs + ((bb) * 2 + (kk)) * 8192 + wave * 512), 16, 0, 0);      \
  __builtin_amdgcn_global_load_lds(                                               \
      (const GLOBAL_AS void*)(B + bbase + (size_t)128 * 2048 + (k0) + (kk) * 32), \
      (LDS_AS void*)(Bs + ((bb) * 2 + (kk)) * 8192 + 4096 + wave * 512), 16, 0, 0);\
} while (0)

#define PHASE_BT(bb, kk, SEN, sbb, skk, sk0, VM) do {                             \
  WAITVM(VM);                                                                     \
  BARX();                                                                         \
  half8_t af[4], bf[4];                                                           \
  const _Float16* pA_ = As + ((bb) * 2 + (kk)) * 4096 +                           \
                        (wr * 64 + m16) * 32 + pseg8;                             \
  const _Float16* pB_ = Bs + ((bb) * 2 + (kk)) * 8192 +                           \
                        (wc * 64 + m16) * 32 + pseg8;                             \
  af[0] = *(const half8_t*)(pA_);        af[1] = *(const half8_t*)(pA_ + 512);    \
  af[2] = *(const half8_t*)(pA_ + 1024); af[3] = *(const half8_t*)(pA_ + 1536);   \
  bf[0] = *(const half8_t*)(pB_);        bf[1] = *(const half8_t*)(pB_ + 512);    \
  bf[2] = *(const half8_t*)(pB_ + 1024); bf[3] = *(const half8_t*)(pB_ + 1536);   \
  if (SEN) STGBT(sbb, skk, sk0);                                                  \
  WAITL(0);                                                                       \
  __builtin_amdgcn_s_setprio(1);                                                  \
  _Pragma("unroll")                                                               \
  for (int i_ = 0; i_ < 4; ++i_)                                                  \
    _Pragma("unroll")                                                             \
    for (int j_ = 0; j_ < 4; ++j_)                                                \
      acc[i_][j_] = __builtin_amdgcn_mfma_f32_16x16x32_f16(                       \
          af[i_], bf[j_], acc[i_][j_], 0, 0, 0);                                  \
  __builtin_amdgcn_s_setprio(0);                                                  \
} while (0)

__global__ __launch_bounds__(512, 2) void hgemm_bt_8p(const _Float16* __restrict__ A,
                                                      const _Float16* __restrict__ B,
                                                      float* __restrict__ C) {
  const int K = 2048, N = 2048;
  __shared__ _Float16 As[16384];  // [buf][kk][128][32]
  __shared__ _Float16 Bs[32768];  // [buf][kk][256][32]

  const int tid = threadIdx.x;
  const int lane = tid & 63;
  const int wave = tid >> 6;
  const int wr = wave >> 2;
  const int wc = wave & 3;
  const int m16 = lane & 15, quad = lane >> 4;
  const int row0 = blockIdx.y * 128, col0 = blockIdx.x * 256;
  const int pseg8 = (quad ^ ((m16 >> 1) & 3)) * 8;

  const int r_ld = tid >> 2;
  const int sseg = (tid & 3) ^ ((tid >> 3) & 3);
  const size_t abase = (size_t)(row0 + r_ld) * K + sseg * 8;
  const size_t bbase = (size_t)(col0 + r_ld) * K + sseg * 8;

  f32x4 acc[4][4];
#pragma unroll
  for (int i = 0; i < 4; ++i)
#pragma unroll
    for (int j = 0; j < 4; ++j) acc[i][j] = (f32x4){0.f, 0.f, 0.f, 0.f};

  STGBT(0, 0, 0); STGBT(0, 1, 0); STGBT(1, 0, 64);

  for (int t = 0; t < 30; ++t) {
    const int bb = t & 1;
    const int k0 = t * 64;
    PHASE_BT(bb, 0, 1, bb ^ 1, 1, k0 + 64, 6);
    PHASE_BT(bb, 1, 1, bb, 0, k0 + 128, 6);
  }
  PHASE_BT(0, 0, 1, 1, 1, 1984, 6);
  PHASE_BT(0, 1, 0, 0, 0, 0, 6);
  PHASE_BT(1, 0, 0, 0, 0, 0, 3);
  PHASE_BT(1, 1, 0, 0, 0, 0, 0);

#pragma unroll
  for (int i = 0; i < 4; ++i)
#pragma unroll
    for (int j = 0; j < 4; ++j) {
      int col = col0 + wc * 64 + j * 16 + m16;
      int rowb = row0 + wr * 64 + i * 16 + quad * 4;
#pragma unroll
      for (int r = 0; r < 4; ++r) C[(size_t)(rowb + r) * N + col] = acc[i][j][r];
    }
}

// ---------------------------------------------------------------------------
// RoPE + token-softmax on kT [1024 dims][4096 tokens] fp16, in place.
// ---------------------------------------------------------------------------
__global__ __launch_bounds__(256) void k_rope_softmax_T(_Float16* __restrict__ kT,
                                                        const float* __restrict__ fcT) {
  int bi = blockIdx.x;
  int b = bi & 1, pr = bi >> 1;
  int d0 = pr * 2, dl = d0 & 127;
  int t = threadIdx.x;
  size_t r0 = (size_t)d0 * MTOK + b * SEQ + t * 8;
  size_t r1 = r0 + MTOK;
  half8_t x0v = *(half8_t*)&kT[r0];
  half8_t x1v = *(half8_t*)&kT[r1];
  int s8 = t * 8;
  float4 ca = *(const float4*)&fcT[(size_t)dl * SEQ + s8];
  float4 cb = *(const float4*)&fcT[(size_t)dl * SEQ + s8 + 4];
  float4 sa = *(const float4*)&fcT[(size_t)(dl + 1) * SEQ + s8];
  float4 sb = *(const float4*)&fcT[(size_t)(dl + 1) * SEQ + s8 + 4];
  float cc[8] = {ca.x, ca.y, ca.z, ca.w, cb.x, cb.y, cb.z, cb.w};
  float ss[8] = {sa.x, sa.y, sa.z, sa.w, sb.x, sb.y, sb.z, sb.w};
  float e0[8], e1[8];
  float sum0 = 0.f, sum1 = 0.f;
#pragma unroll
  for (int j = 0; j < 8; ++j) {
    float x0 = (float)x0v[j], x1 = (float)x1v[j];
    float o0 = x0 * cc[j] - x1 * ss[j];
    float o1 = x0 * ss[j] + x1 * cc[j];
    e0[j] = expf(o0); e1[j] = expf(o1);
    sum0 += e0[j]; sum1 += e1[j];
  }
#pragma unroll
  for (int off = 1; off < 64; off <<= 1) {
    sum0 += __shfl_xor(sum0, off);
    sum1 += __shfl_xor(sum1, off);
  }
  __shared__ float red[8];
  if ((t & 63) == 0) { red[(t >> 6) * 2] = sum0; red[(t >> 6) * 2 + 1] = sum1; }
  __syncthreads();
  float S0 = red[0] + red[2] + red[4] + red[6];
  float S1 = red[1] + red[3] + red[5] + red[7];
  float i0 = 1.f / S0, i1 = 1.f / S1;
  half8_t w0, w1;
#pragma unroll
  for (int j = 0; j < 8; ++j) {
    w0[j] = (_Float16)(e0[j] * i0);
    w1[j] = (_Float16)(e1[j] * i1);
  }
  *(half8_t*)&kT[r0] = w0;
  *(half8_t*)&kT[r1] = w1;
}

// ---------------------------------------------------------------------------
// kT [1024][4096] -> kh [4096][1024]  (fp16 tile transpose)
// ---------------------------------------------------------------------------
__global__ __launch_bounds__(256) void transpose_k(const _Float16* __restrict__ kT,
                                                   _Float16* __restrict__ kh) {
  __shared__ _Float16 T[64][65];
  int t0 = blockIdx.x * 64, d0 = blockIdx.y * 64;
  int t = threadIdx.x;
  int r = t >> 3, c8 = (t & 7) * 8;
#pragma unroll
  for (int p = 0; p < 2; ++p) {
    int dr = p * 32 + r;
    half8_t v = *(const half8_t*)&kT[(size_t)(d0 + dr) * MTOK + t0 + c8];
#pragma unroll
    for (int j = 0; j < 8; ++j) T[c8 + j][dr] = v[j];
  }
  __syncthreads();
#pragma unroll
  for (int p = 0; p < 2; ++p) {
    int tr = p * 32 + r;
    half8_t v;
#pragma unroll
    for (int j = 0; j < 8; ++j) v[j] = T[tr][c8 + j];
    *(half8_t*)&kh[(size_t)(t0 + tr) * KVD + d0 + c8] = v;
  }
}

// ---------------------------------------------------------------------------
// kvT[e][d] = sum_c v[c,e]*k[c,d] per (b,kvh,chunk). MFMA fp16, M=N=K=128.
// ---------------------------------------------------------------------------
__global__ __launch_bounds__(256) void kv_chunk_mfma(const _Float16* __restrict__ vT,
                                                     const _Float16* __restrict__ kT,
                                                     float* __restrict__ kvT) {
  __shared__ _Float16 As[2][128 * 32];
  __shared__ _Float16 Bs[2][128 * 32];
  int bi = blockIdx.x;
  int n = bi & 15, kvh = (bi >> 4) & 7, b = bi >> 7;
  int tok0 = b * SEQ + n * CHUNK;
  const int tid = threadIdx.x;
  const int lane = tid & 63;
  const int wave = tid >> 6;
  const int wr = wave & 1, wc = wave >> 1;
  const int m16 = lane & 15, quad = lane >> 4;
  const int qsw8 = (quad ^ ((m16 >> 1) & 3)) * 8;

  f32x4 acc[4][4];
#pragma unroll
  for (int i = 0; i < 4; ++i)
#pragma unroll
    for (int j = 0; j < 4; ++j) acc[i][j] = (f32x4){0.f, 0.f, 0.f, 0.f};

  const int r_ld = tid >> 2;
  const int sseg = (tid & 3) ^ ((tid >> 3) & 3);
  const size_t a_base = (size_t)(kvh * HD + r_ld) * MTOK + tok0 + sseg * 8;

#pragma unroll
  for (int i = 0; i < 2; ++i) {
    __builtin_amdgcn_global_load_lds(
        (const GLOBAL_AS void*)(vT + a_base + (size_t)i * 64 * MTOK),
        (LDS_AS void*)(&As[0][0] + i * 2048 + wave * 512), 16, 0, 0);
    __builtin_amdgcn_global_load_lds(
        (const GLOBAL_AS void*)(kT + a_base + (size_t)i * 64 * MTOK),
        (LDS_AS void*)(&Bs[0][0] + i * 2048 + wave * 512), 16, 0, 0);
  }

#pragma unroll
  for (int s = 0; s < 4; ++s) {
    WAITVM(0);
    BARX();
    if (s < 3) {
      const int k0 = (s + 1) * 32;
      const int bb = (s + 1) & 1;
#pragma unroll
      for (int i = 0; i < 2; ++i) {
        __builtin_amdgcn_global_load_lds(
            (const GLOBAL_AS void*)(vT + a_base + (size_t)i * 64 * MTOK + k0),
            (LDS_AS void*)(&As[bb][0] + i * 2048 + wave * 512), 16, 0, 0);
        __builtin_amdgcn_global_load_lds(
            (const GLOBAL_AS void*)(kT + a_base + (size_t)i * 64 * MTOK + k0),
            (LDS_AS void*)(&Bs[bb][0] + i * 2048 + wave * 512), 16, 0, 0);
      }
    }
    const _Float16* ra = &As[s & 1][0];
    const _Float16* rb = &Bs[s & 1][0];
    half8_t af[4], bf[4];
#pragma unroll
    for (int i = 0; i < 4; ++i) {
      af[i] = *(const half8_t*)&ra[(wr * 64 + i * 16 + m16) * 32 + qsw8];
      bf[i] = *(const half8_t*)&rb[(wc * 64 + i * 16 + m16) * 32 + qsw8];
    }
#pragma unroll
    for (int i = 0; i < 4; ++i)
#pragma unroll
      for (int j = 0; j < 4; ++j)
        acc[i][j] = __builtin_amdgcn_mfma_f32_16x16x32_f16(af[i], bf[j], acc[i][j], 0, 0, 0);
  }
#pragma unroll
  for (int i = 0; i < 4; ++i)
#pragma unroll
    for (int j = 0; j < 4; ++j) {
      int col = wc * 64 + j * 16 + m16;
      int rowb = wr * 64 + i * 16 + quad * 4;
#pragma unroll
      for (int r = 0; r < 4; ++r)
        kvT[(size_t)bi * 16384 + (size_t)(rowb + r) * 128 + col] = acc[i][j][r];
    }
}

// ---------------------------------------------------------------------------
// Exclusive chunk-cumsum of kvT (f32), emitting fp16 cumT. grid 1024x256.
// ---------------------------------------------------------------------------
__global__ __launch_bounds__(256) void cumsum_h(const float* __restrict__ kvT,
                                                _Float16* __restrict__ cumh) {
  int gid = blockIdx.x * 256 + threadIdx.x;
  int bk = gid >> 14, idx = gid & 16383;
  size_t base = (size_t)bk * NCHUNK * 16384 + idx;
  float run = 0.f;
#pragma unroll
  for (int n = 0; n < NCHUNK; ++n) {
    cumh[base + (size_t)n * 16384] = (_Float16)run;
    run += kvT[base + (size_t)n * 16384];
  }
}

// ---------------------------------------------------------------------------
// Fused scores+output per (b,h,chunk). v3 (round-7 verified): 8 uniform steps,
// dual-B in steps 0-3 (shared q fragments), Qs/Ss aliased. LDS 64 KB.
// ---------------------------------------------------------------------------
__global__ __launch_bounds__(256) void attn_fused(const _Float16* __restrict__ qh,
                                                  const _Float16* __restrict__ kh,
                                                  const _Float16* __restrict__ cumh,
                                                  const _Float16* __restrict__ vT,
                                                  _Float16* __restrict__ ath) {
  __shared__ _Float16 QS[128 * 128];   // Qs for steps 0-3, then Ss for 4-7
  __shared__ _Float16 Bk[2][128 * 32];
  __shared__ _Float16 Bc[2][128 * 32];
  int bi = blockIdx.x;
  int n = bi & 15, h = (bi >> 4) & 15, b = bi >> 8;
  int kvh = h >> 1;
  int tok0 = b * SEQ + n * CHUNK;
  const int tid = threadIdx.x;
  const int lane = tid & 63;
  const int wave = tid >> 6;
  const int wr = wave & 1, wc = wave >> 1;
  const int m16 = lane & 15, quad = lane >> 4;
  const int qsw8 = (quad ^ ((m16 >> 1) & 3)) * 8;
  const int r_ld = tid >> 2;
  const int sseg = (tid & 3) ^ ((tid >> 3) & 3);

  f32x4 acc[4][4];   // output accumulator (inter + intra)
  f32x4 accs[4][4];  // scores accumulator
#pragma unroll
  for (int i = 0; i < 4; ++i)
#pragma unroll
    for (int j = 0; j < 4; ++j) {
      acc[i][j] = (f32x4){0.f, 0.f, 0.f, 0.f};
      accs[i][j] = (f32x4){0.f, 0.f, 0.f, 0.f};
    }

  const int qrow = tid >> 4;
  const int qsl = (tid & 15) ^ (qrow & 7);
  const size_t qsrc = (size_t)(tok0 + qrow) * DIMV + h * HD + qsl * 8;
#pragma unroll
  for (int p = 0; p < 8; ++p)
    __builtin_amdgcn_global_load_lds(
        (const GLOBAL_AS void*)(qh + qsrc + (size_t)p * 16 * DIMV),
        (LDS_AS void*)(QS + p * 2048 + wave * 512), 16, 0, 0);

  const size_t kbase = (size_t)(tok0 + r_ld) * KVD + kvh * HD + sseg * 8;
  const size_t cbase = ((size_t)((b * 8 + kvh) * 16 + n)) * 16384 + (size_t)r_ld * 128 + sseg * 8;
  const size_t vbase = (size_t)(kvh * HD + r_ld) * MTOK + tok0 + sseg * 8;

#pragma unroll
  for (int i = 0; i < 2; ++i) {
    __builtin_amdgcn_global_load_lds(
        (const GLOBAL_AS void*)(kh + kbase + (size_t)i * 64 * KVD),
        (LDS_AS void*)(&Bk[0][0] + i * 2048 + wave * 512), 16, 0, 0);
    __builtin_amdgcn_global_load_lds(
        (const GLOBAL_AS void*)(cumh + cbase + (size_t)i * 64 * 128),
        (LDS_AS void*)(&Bc[0][0] + i * 2048 + wave * 512), 16, 0, 0);
  }

#pragma unroll
  for (int s = 0; s < 8; ++s) {
    WAITVM(0);
    BARX();
    if (s < 3) {
      const int k0 = (s + 1) * 32;
      const int bb = (s + 1) & 1;
#pragma unroll
      for (int i = 0; i < 2; ++i) {
        __builtin_amdgcn_global_load_lds(
            (const GLOBAL_AS void*)(kh + kbase + (size_t)i * 64 * KVD + k0),
            (LDS_AS void*)(&Bk[bb][0] + i * 2048 + wave * 512), 16, 0, 0);
        __builtin_amdgcn_global_load_lds(
            (const GLOBAL_AS void*)(cumh + cbase + (size_t)i * 64 * 128 + k0),
            (LDS_AS void*)(&Bc[bb][0] + i * 2048 + wave * 512), 16, 0, 0);
      }
    } else if (s < 7) {
      const int k0 = (s - 3) * 32;
      const int bb = (s + 1) & 1;
#pragma unroll
      for (int i = 0; i < 2; ++i)
        __builtin_amdgcn_global_load_lds(
            (const GLOBAL_AS void*)(vT + vbase + (size_t)i * 64 * MTOK + k0),
            (LDS_AS void*)(&Bk[bb][0] + i * 2048 + wave * 512), 16, 0, 0);
    }
    if (s < 4) {
      half8_t af[4], bfk[4], bfc[4];
      const int sl4 = s * 4;
      const _Float16* rk = &Bk[s & 1][0];
      const _Float16* rc = &Bc[s & 1][0];
#pragma unroll
      for (int i = 0; i < 4; ++i) {
        int row = wr * 64 + i * 16 + m16;
        af[i] = *(const half8_t*)&QS[row * 128 + ((sl4 + quad) ^ (m16 & 7)) * 8];
        bfk[i] = *(const half8_t*)&rk[(wc * 64 + i * 16 + m16) * 32 + qsw8];
        bfc[i] = *(const half8_t*)&rc[(wc * 64 + i * 16 + m16) * 32 + qsw8];
      }
#pragma unroll
      for (int i = 0; i < 4; ++i)
#pragma unroll
        for (int j = 0; j < 4; ++j) {
          accs[i][j] = __builtin_amdgcn_mfma_f32_16x16x32_f16(af[i], bfk[j], accs[i][j], 0, 0, 0);
          acc[i][j] = __builtin_amdgcn_mfma_f32_16x16x32_f16(af[i], bfc[j], acc[i][j], 0, 0, 0);
        }
      if (s == 3) {
        BARX();  // all waves done reading QS (q) before aliasing it with Ss
#pragma unroll
        for (int i = 0; i < 4; ++i)
#pragma unroll
          for (int j = 0; j < 4; ++j) {
            int col = wc * 64 + j * 16 + m16;
            int rowb = wr * 64 + i * 16 + quad * 4;
#pragma unroll
            for (int r = 0; r < 4; ++r) {
              int row = rowb + r;
              float v = (col <= row) ? accs[i][j][r] : 0.f;
              int sp = (col >> 3) ^ (row & 7);
              QS[row * 128 + sp * 8 + (col & 7)] = (_Float16)v;
            }
          }
        WAITL(0);  // drain Ss writes before next step's barrier publishes them
      }
    } else {
      half8_t af[4], bf[4];
      const int sl4 = (s - 4) * 4;
      const _Float16* rk = &Bk[s & 1][0];
#pragma unroll
      for (int i = 0; i < 4; ++i) {
        int row = wr * 64 + i * 16 + m16;
        af[i] = *(const half8_t*)&QS[row * 128 + ((sl4 + quad) ^ (m16 & 7)) * 8];
        bf[i] = *(const half8_t*)&rk[(wc * 64 + i * 16 + m16) * 32 + qsw8];
      }
#pragma unroll
      for (int i = 0; i < 4; ++i)
#pragma unroll
        for (int j = 0; j < 4; ++j)
          acc[i][j] = __builtin_amdgcn_mfma_f32_16x16x32_f16(af[i], bf[j], acc[i][j], 0, 0, 0);
    }
  }

#pragma unroll
  for (int i = 0; i < 4; ++i)
#pragma unroll
    for (int j = 0; j < 4; ++j) {
      int col = wc * 64 + j * 16 + m16;
      int rowb = wr * 64 + i * 16 + quad * 4;
#pragma unroll
      for (int r = 0; r < 4; ++r)
        ath[(size_t)(tok0 + rowb + r) * DIMV + h * HD + col] = (_Float16)acc[i][j][r];
    }
}

// ---------------------------------------------------------------------------
extern "C" void kernel_launch(void* const* d_in, const int* in_sizes, int n_in,
                              void* d_out, int out_size, void* d_ws, size_t ws_size,
                              hipStream_t stream) {
  const float* x  = (const float*)d_in[0];
  const float* fc = (const float*)d_in[1];
  const float* wq = (const float*)d_in[2];
  const float* wk = (const float*)d_in[3];
  const float* wv = (const float*)d_in[4];
  const float* wo = (const float*)d_in[5];
  float* out = (float*)d_out;

  char* p = (char*)d_ws;
  _Float16* xh    = (_Float16*)p;  p += 16777216;  // 4096x2048
  _Float16* wqkvh = (_Float16*)p;  p += 16777216;  // 4096x2048 (wq|wk|wv)
  _Float16* woh   = (_Float16*)p;  p += 8388608;   // 2048x2048
  _Float16* qh    = (_Float16*)p;  p += 16777216;  // 4096x2048
  _Float16* kT    = (_Float16*)p;  p += 8388608;   // 1024x4096
  _Float16* kh    = (_Float16*)p;  p += 8388608;   // 4096x1024
  _Float16* vT    = (_Float16*)p;  p += 8388608;   // 1024x4096
  float*    kvT   = (float*)p;     p += 16777216;  // 256x128x128 f32
  _Float16* cumh  = (_Float16*)p;  p += 8388608;
  _Float16* ath   = (_Float16*)p;  p += 16777216;  // 4096x2048
  float*    fcT   = (float*)p;     p += 1048576;   // 128x2048 f32

  // casts + fc transpose in one launch
  cast_all<<<10304, 256, 0, stream>>>(x, wq, wk, wv, wo, xh, wqkvh, woh, fc, fcT);

  // fused QKV projection + q RoPE/softmax (v2: 2-phase K-tiles, 32-MFMA clusters)
  hgemm_qkv_8p<<<dim3(16, 16), 512, 0, stream>>>(xh, wqkvh, fc, qh, kT, vT);

  // k rope + softmax, then transpose to token-major
  k_rope_softmax_T<<<1024, 256, 0, stream>>>(kT, fcT);
  transpose_k<<<dim3(64, 16), 256, 0, stream>>>(kT, kh);

  // chunked linear attention
  kv_chunk_mfma<<<256, 256, 0, stream>>>(vT, kT, kvT);
  cumsum_h<<<1024, 256, 0, stream>>>(kvT, cumh);

  // fused attention core (v3: 8 steps, dual-B, Qs/Ss aliased)
  attn_fused<<<512, 256, 0, stream>>>(qh, kh, cumh, vT, ath);

  // output projection
  hgemm_bt_8p<<<dim3(8, 32), 512, 0, stream>>>(ath, woh, out);
}

// Round 11
// 280.939 us; speedup vs baseline: 1.0413x; 1.0073x over previous
//
#include <hip/hip_runtime.h>
#include <math.h>

#define DIMV 2048
#define NHEAD 16
#define NKV 8
#define HD 128
#define BATCH 2
#define SEQ 2048
#define CHUNK 128
#define NCHUNK 16
#define MTOK 4096  // BATCH*SEQ
#define KVD (NKV * HD)  // 1024

typedef _Float16 half8_t __attribute__((ext_vector_type(8)));
typedef _Float16 half4_t __attribute__((ext_vector_type(4)));
typedef _Float16 half2_t __attribute__((ext_vector_type(2)));
typedef float f32x4 __attribute__((ext_vector_type(4)));

#define GLOBAL_AS __attribute__((address_space(1)))
#define LDS_AS __attribute__((address_space(3)))

#define BARX() __builtin_amdgcn_s_barrier()
#define WAITL(n) asm volatile("s_waitcnt lgkmcnt(" #n ")" ::: "memory")
#define WAITVM(n) asm volatile("s_waitcnt vmcnt(" #n ")" ::: "memory")

// ---------------------------------------------------------------------------
// All five f32->f16 casts + fc transpose in one launch. grid 10304 x 256.
// ---------------------------------------------------------------------------
__global__ __launch_bounds__(256) void cast_all(const float* __restrict__ x,
                                                const float* __restrict__ wq,
                                                const float* __restrict__ wk,
                                                const float* __restrict__ wv,
                                                const float* __restrict__ wo,
                                                _Float16* __restrict__ xh,
                                                _Float16* __restrict__ wqkvh,
                                                _Float16* __restrict__ woh,
                                                const float* __restrict__ fc,
                                                float* __restrict__ fcT) {
  __shared__ float T[64][65];
  if (blockIdx.x >= 10240) {
    int q = blockIdx.x - 10240;
    int s0 = (q & 31) * 64, d0 = (q >> 5) * 64;
    int t = threadIdx.x;
    int r = t >> 4, c4 = (t & 15) * 4;
#pragma unroll
    for (int p = 0; p < 4; ++p) {
      int sr = p * 16 + r;
      float4 v = *(const float4*)&fc[(size_t)(s0 + sr) * 128 + d0 + c4];
      T[sr][c4] = v.x; T[sr][c4 + 1] = v.y; T[sr][c4 + 2] = v.z; T[sr][c4 + 3] = v.w;
    }
    __syncthreads();
#pragma unroll
    for (int p = 0; p < 4; ++p) {
      int dr = p * 16 + r;
      float4 v = make_float4(T[c4][dr], T[c4 + 1][dr], T[c4 + 2][dr], T[c4 + 3][dr]);
      *(float4*)&fcT[(size_t)(d0 + dr) * SEQ + s0 + c4] = v;
    }
    return;
  }
  long i = (long)(blockIdx.x * 256 + threadIdx.x) * 8;
  const float* src;
  _Float16* dst;
  long off;
  if (i < 8388608)        { src = x;  dst = xh;              off = 0; }
  else if (i < 12582912)  { src = wq; dst = wqkvh;           off = 8388608; }
  else if (i < 14680064)  { src = wk; dst = wqkvh + 4194304; off = 12582912; }
  else if (i < 16777216)  { src = wv; dst = wqkvh + 6291456; off = 14680064; }
  else                    { src = wo; dst = woh;             off = 16777216; }
  long e = i - off;
  float4 a = *(const float4*)&src[e];
  float4 b = *(const float4*)&src[e + 4];
  half8_t h = {(_Float16)a.x, (_Float16)a.y, (_Float16)a.z, (_Float16)a.w,
               (_Float16)b.x, (_Float16)b.y, (_Float16)b.z, (_Float16)b.w};
  *(half8_t*)&dst[e] = h;
}

// ---------------------------------------------------------------------------
// Fused QKV projection, 256x256 tile, BK=64. v2 (round-8 verified, 283 us
// total): TWO phases per K-tile (32-MFMA clusters).
// Per phase: 12 ds_read_b128 (8 A rows + 4 B) + 4 global_load_lds staging +
// counted vmcnt(8) + barrier + lgkm(0) + setprio + 32 MFMA + barrier.
// Ledger: steady-state 12 outstanding at each wait, oldest 4 must land ->
// vmcnt(8); tail 8 -> 4 -> 0 -> 0. Swizzle (row>>1)&3 XOR (0 conflicts).
// grid dim3(16,16) x 512 threads.
// ---------------------------------------------------------------------------
#define STG_A(bb, kk, i, k0)                                                      \
  __builtin_amdgcn_global_load_lds(                                               \
      (const GLOBAL_AS void*)(A + aoff + (size_t)(i) * 128 * 2048 + (k0) + (kk) * 32), \
      (LDS_AS void*)(As + ((bb) * 2 + (kk)) * 8192 + (i) * 4096 + wave * 512), 16, 0, 0)
#define STG_B(bb, kk, i, k0)                                                      \
  __builtin_amdgcn_global_load_lds(                                               \
      (const GLOBAL_AS void*)(B + boff + (size_t)(i) * 128 * 2048 + (k0) + (kk) * 32), \
      (LDS_AS void*)(Bs + ((bb) * 2 + (kk)) * 8192 + (i) * 4096 + wave * 512), 16, 0, 0)

// One phase: consume (bb,kk); optionally stage 4 loads into (sbb,skk) at sk0.
#define KT2(bb, kk, SEN, sbb, skk, sk0, VM) do {                                  \
  half8_t af[8], bf[4];                                                           \
  const _Float16* pA_ = As + ((bb) * 2 + (kk)) * 8192 +                           \
                        (wr * 128 + m16) * 32 + pseg8;                            \
  const _Float16* pB_ = Bs + ((bb) * 2 + (kk)) * 8192 +                           \
                        (wc * 64 + m16) * 32 + pseg8;                             \
  _Pragma("unroll")                                                               \
  for (int m_ = 0; m_ < 8; ++m_) af[m_] = *(const half8_t*)(pA_ + m_ * 512);      \
  _Pragma("unroll")                                                               \
  for (int j_ = 0; j_ < 4; ++j_) bf[j_] = *(const half8_t*)(pB_ + j_ * 512);      \
  if (SEN) {                                                                      \
    STG_A(sbb, skk, 0, sk0); STG_A(sbb, skk, 1, sk0);                             \
    STG_B(sbb, skk, 0, sk0); STG_B(sbb, skk, 1, sk0);                             \
  }                                                                               \
  WAITVM(VM);                                                                     \
  BARX(); WAITL(0);                                                               \
  __builtin_amdgcn_s_setprio(1);                                                  \
  _Pragma("unroll")                                                               \
  for (int m_ = 0; m_ < 8; ++m_)                                                  \
    _Pragma("unroll")                                                             \
    for (int j_ = 0; j_ < 4; ++j_)                                                \
      acc[m_][j_] = __builtin_amdgcn_mfma_f32_16x16x32_f16(                       \
          af[m_], bf[j_], acc[m_][j_], 0, 0, 0);                                  \
  __builtin_amdgcn_s_setprio(0);                                                  \
  BARX();                                                                         \
} while (0)

__global__ __launch_bounds__(512, 2) void hgemm_qkv_8p(const _Float16* __restrict__ A,
                                                       const _Float16* __restrict__ B,
                                                       const float* __restrict__ fc,
                                                       _Float16* __restrict__ qh,
                                                       _Float16* __restrict__ kT,
                                                       _Float16* __restrict__ vT) {
  const int K = 2048;
  __shared__ _Float16 As[32768];  // [buf][kk][256][32]
  __shared__ _Float16 Bs[32768];
  __shared__ float qsum[4][256];

  const int tid = threadIdx.x;
  const int lane = tid & 63;
  const int wave = tid >> 6;
  const int wr = wave >> 2;   // 0..1 : 128-row half
  const int wc = wave & 3;    // 0..3 : 64-col quarter
  const int m16 = lane & 15, quad = lane >> 4;
  const int row0 = blockIdx.y * 256, col0 = blockIdx.x * 256;
  // read-side seg: keyed on (row>>1)&3 = (m16>>1)&3  (64B rows)
  const int pseg8 = (quad ^ ((m16 >> 1) & 3)) * 8;

  // staging address (source pre-swizzled with the same (row>>1)&3 key)
  const int r_ld = tid >> 2;                  // 0..127
  const int sseg = (tid & 3) ^ ((tid >> 3) & 3);
  const size_t aoff = (size_t)(row0 + r_ld) * K + sseg * 8;
  const size_t boff = (size_t)(col0 + r_ld) * K + sseg * 8;

  f32x4 acc[8][4];
#pragma unroll
  for (int m = 0; m < 8; ++m)
#pragma unroll
    for (int j = 0; j < 4; ++j) acc[m][j] = (f32x4){0.f, 0.f, 0.f, 0.f};

  // prologue: kk0(0), kk1(0), kk0(1)  (12 loads)
  STG_A(0, 0, 0, 0); STG_A(0, 0, 1, 0); STG_B(0, 0, 0, 0); STG_B(0, 0, 1, 0);
  STG_A(0, 1, 0, 0); STG_A(0, 1, 1, 0); STG_B(0, 1, 0, 0); STG_B(0, 1, 1, 0);
  STG_A(1, 0, 0, 64); STG_A(1, 0, 1, 64); STG_B(1, 0, 0, 64); STG_B(1, 0, 1, 64);
  WAITVM(8);  // kk0(0) landed; kk1(0)+kk0(1) stay in flight
  BARX();

  for (int t = 0; t < 30; ++t) {
    const int bb = t & 1;
    const int k0 = t * 64;
    KT2(bb, 0, 1, bb ^ 1, 1, k0 + 64, 8);   // consume kk0(t); stage kk1(t+1)
    KT2(bb, 1, 1, bb, 0, k0 + 128, 8);      // consume kk1(t); stage kk0(t+2)
  }
  KT2(0, 0, 1, 1, 1, 1984, 8);  // t=30 PH1: stage kk1(31)
  KT2(0, 1, 0, 0, 0, 0, 4);     // t=30 PH2: kk0(31) must land
  KT2(1, 0, 0, 0, 0, 0, 0);     // t=31 PH1: kk1(31) must land
  KT2(1, 1, 0, 0, 0, 0, 0);     // t=31 PH2: drain

  // ---- epilogue ----
  // row_l(m,r) = wr*128 + m*16 + quad*4 + r ; col_l(j) = wc*64 + j*16 + m16
  if (col0 < 2048) {
    const float sc = 0.08838834764831845f;  // 128^-0.5
    float psum[8][4];
#pragma unroll
    for (int m = 0; m < 8; ++m)
#pragma unroll
      for (int r = 0; r < 4; ++r) psum[m][r] = 0.f;
#pragma unroll
    for (int m = 0; m < 8; ++m)
#pragma unroll
      for (int j = 0; j < 4; ++j) {
        int dl2 = (wc * 64 + j * 16 + m16) & 126;
#pragma unroll
        for (int r = 0; r < 4; ++r) {
          float val = acc[m][j][r];
          float par = __shfl_xor(val, 1);
          int row_l = wr * 128 + m * 16 + quad * 4 + r;
          int s_tok = (row0 + row_l) & (SEQ - 1);
          float2 cs = *(const float2*)&fc[(size_t)s_tok * 128 + dl2];
          float o = val * cs.x + par * ((m16 & 1) ? cs.y : -cs.y);
          float e = __expf(o * sc);
          acc[m][j][r] = e;
          psum[m][r] += e;
        }
      }
#pragma unroll
    for (int mm = 1; mm < 16; mm <<= 1)
#pragma unroll
      for (int m = 0; m < 8; ++m)
#pragma unroll
        for (int r = 0; r < 4; ++r) psum[m][r] += __shfl_xor(psum[m][r], mm);
    if (m16 == 0) {
#pragma unroll
      for (int m = 0; m < 8; ++m)
#pragma unroll
        for (int r = 0; r < 4; ++r) {
          int row_l = wr * 128 + m * 16 + quad * 4 + r;
          qsum[wc][row_l] = psum[m][r];
        }
    }
    __syncthreads();
#pragma unroll
    for (int m = 0; m < 8; ++m)
#pragma unroll
      for (int r = 0; r < 4; ++r) {
        int row_l = wr * 128 + m * 16 + quad * 4 + r;
        psum[m][r] = 1.f / (qsum[wc & 2][row_l] + qsum[(wc & 2) | 1][row_l]);
      }
#pragma unroll
    for (int m = 0; m < 8; ++m)
#pragma unroll
      for (int j = 0; j < 4; ++j) {
        int col = col0 + wc * 64 + j * 16 + m16;
#pragma unroll
        for (int r = 0; r < 4; ++r) {
          int row_l = wr * 128 + m * 16 + quad * 4 + r;
          qh[(size_t)(row0 + row_l) * DIMV + col] = (_Float16)(acc[m][j][r] * psum[m][r]);
        }
      }
  } else {
#pragma unroll
    for (int m = 0; m < 8; ++m)
#pragma unroll
      for (int j = 0; j < 4; ++j) {
        int col = col0 + wc * 64 + j * 16 + m16;
        int rowb = row0 + wr * 128 + m * 16 + quad * 4;
        half4_t hv = {(_Float16)acc[m][j][0], (_Float16)acc[m][j][1],
                      (_Float16)acc[m][j][2], (_Float16)acc[m][j][3]};
        if (col0 < 3072) {
          *(half4_t*)&kT[(size_t)(col - 2048) * MTOK + rowb] = hv;
        } else {
          *(half4_t*)&vT[(size_t)(col - 3072) * MTOK + rowb] = hv;
        }
      }
  }
}

// ---------------------------------------------------------------------------
// Output GEMM, KTILE-class schedule (round-5 verified win).
// ---------------------------------------------------------------------------
#define STGBT(bb, kk, k0) do {                                                    \
  __builtin_amdgcn_global_load_lds(                                               \
      (const GLOBAL_AS void*)(A + abase + (k0) + (kk) * 32),                      \
      (LDS_AS void*)(As + ((bb) * 2 + (kk)) * 4096 + wave * 512), 16, 0, 0);      \
  __builtin_amdgcn_global_load_lds(                                               \
      (const GLOBAL_AS void*)(B + bbase + (k0) + (kk) * 32),                      \
      (LDS_AS void*)(Bs + ((bb) * 2 + (kk)) * 8192 + wave * 512), 16, 0, 0);      \
  __builtin_amdgcn_global_load_lds(                                               \
      (const GLOBAL_AS void*)(B + bbase + (size_t)128 * 2048 + (k0) + (kk) * 32), \
      (LDS_AS void*)(Bs + ((bb) * 2 + (kk)) * 8192 + 4096 + wave * 512), 16, 0, 0);\
} while (0)

#define PHASE_BT(bb, kk, SEN, sbb, skk, sk0, VM) do {                             \
  WAITVM(VM);                                                                     \
  BARX();                                                                         \
  half8_t af[4], bf[4];                                                           \
  const _Float16* pA_ = As + ((bb) * 2 + (kk)) * 4096 +                           \
                        (wr * 64 + m16) * 32 + pseg8;                             \
  const _Float16* pB_ = Bs + ((bb) * 2 + (kk)) * 8192 +                           \
                        (wc * 64 + m16) * 32 + pseg8;                             \
  af[0] = *(const half8_t*)(pA_);        af[1] = *(const half8_t*)(pA_ + 512);    \
  af[2] = *(const half8_t*)(pA_ + 1024); af[3] = *(const half8_t*)(pA_ + 1536);   \
  bf[0] = *(const half8_t*)(pB_);        bf[1] = *(const half8_t*)(pB_ + 512);    \
  bf[2] = *(const half8_t*)(pB_ + 1024); bf[3] = *(const half8_t*)(pB_ + 1536);   \
  if (SEN) STGBT(sbb, skk, sk0);                                                  \
  WAITL(0);                                                                       \
  __builtin_amdgcn_s_setprio(1);                                                  \
  _Pragma("unroll")                                                               \
  for (int i_ = 0; i_ < 4; ++i_)                                                  \
    _Pragma("unroll")                                                             \
    for (int j_ = 0; j_ < 4; ++j_)                                                \
      acc[i_][j_] = __builtin_amdgcn_mfma_f32_16x16x32_f16(                       \
          af[i_], bf[j_], acc[i_][j_], 0, 0, 0);                                  \
  __builtin_amdgcn_s_setprio(0);                                                  \
} while (0)

__global__ __launch_bounds__(512, 2) void hgemm_bt_8p(const _Float16* __restrict__ A,
                                                      const _Float16* __restrict__ B,
                                                      float* __restrict__ C) {
  const int K = 2048, N = 2048;
  __shared__ _Float16 As[16384];  // [buf][kk][128][32]
  __shared__ _Float16 Bs[32768];  // [buf][kk][256][32]

  const int tid = threadIdx.x;
  const int lane = tid & 63;
  const int wave = tid >> 6;
  const int wr = wave >> 2;
  const int wc = wave & 3;
  const int m16 = lane & 15, quad = lane >> 4;
  const int row0 = blockIdx.y * 128, col0 = blockIdx.x * 256;
  const int pseg8 = (quad ^ ((m16 >> 1) & 3)) * 8;

  const int r_ld = tid >> 2;
  const int sseg = (tid & 3) ^ ((tid >> 3) & 3);
  const size_t abase = (size_t)(row0 + r_ld) * K + sseg * 8;
  const size_t bbase = (size_t)(col0 + r_ld) * K + sseg * 8;

  f32x4 acc[4][4];
#pragma unroll
  for (int i = 0; i < 4; ++i)
#pragma unroll
    for (int j = 0; j < 4; ++j) acc[i][j] = (f32x4){0.f, 0.f, 0.f, 0.f};

  STGBT(0, 0, 0); STGBT(0, 1, 0); STGBT(1, 0, 64);

  for (int t = 0; t < 30; ++t) {
    const int bb = t & 1;
    const int k0 = t * 64;
    PHASE_BT(bb, 0, 1, bb ^ 1, 1, k0 + 64, 6);
    PHASE_BT(bb, 1, 1, bb, 0, k0 + 128, 6);
  }
  PHASE_BT(0, 0, 1, 1, 1, 1984, 6);
  PHASE_BT(0, 1, 0, 0, 0, 0, 6);
  PHASE_BT(1, 0, 0, 0, 0, 0, 3);
  PHASE_BT(1, 1, 0, 0, 0, 0, 0);

#pragma unroll
  for (int i = 0; i < 4; ++i)
#pragma unroll
    for (int j = 0; j < 4; ++j) {
      int col = col0 + wc * 64 + j * 16 + m16;
      int rowb = row0 + wr * 64 + i * 16 + quad * 4;
#pragma unroll
      for (int r = 0; r < 4; ++r) C[(size_t)(rowb + r) * N + col] = acc[i][j][r];
    }
}

// ---------------------------------------------------------------------------
// RoPE + token-softmax on kT [1024 dims][4096 tokens] fp16, in place.
// ---------------------------------------------------------------------------
__global__ __launch_bounds__(256) void k_rope_softmax_T(_Float16* __restrict__ kT,
                                                        const float* __restrict__ fcT) {
  int bi = blockIdx.x;
  int b = bi & 1, pr = bi >> 1;
  int d0 = pr * 2, dl = d0 & 127;
  int t = threadIdx.x;
  size_t r0 = (size_t)d0 * MTOK + b * SEQ + t * 8;
  size_t r1 = r0 + MTOK;
  half8_t x0v = *(half8_t*)&kT[r0];
  half8_t x1v = *(half8_t*)&kT[r1];
  int s8 = t * 8;
  float4 ca = *(const float4*)&fcT[(size_t)dl * SEQ + s8];
  float4 cb = *(const float4*)&fcT[(size_t)dl * SEQ + s8 + 4];
  float4 sa = *(const float4*)&fcT[(size_t)(dl + 1) * SEQ + s8];
  float4 sb = *(const float4*)&fcT[(size_t)(dl + 1) * SEQ + s8 + 4];
  float cc[8] = {ca.x, ca.y, ca.z, ca.w, cb.x, cb.y, cb.z, cb.w};
  float ss[8] = {sa.x, sa.y, sa.z, sa.w, sb.x, sb.y, sb.z, sb.w};
  float e0[8], e1[8];
  float sum0 = 0.f, sum1 = 0.f;
#pragma unroll
  for (int j = 0; j < 8; ++j) {
    float x0 = (float)x0v[j], x1 = (float)x1v[j];
    float o0 = x0 * cc[j] - x1 * ss[j];
    float o1 = x0 * ss[j] + x1 * cc[j];
    e0[j] = expf(o0); e1[j] = expf(o1);
    sum0 += e0[j]; sum1 += e1[j];
  }
#pragma unroll
  for (int off = 1; off < 64; off <<= 1) {
    sum0 += __shfl_xor(sum0, off);
    sum1 += __shfl_xor(sum1, off);
  }
  __shared__ float red[8];
  if ((t & 63) == 0) { red[(t >> 6) * 2] = sum0; red[(t >> 6) * 2 + 1] = sum1; }
  __syncthreads();
  float S0 = red[0] + red[2] + red[4] + red[6];
  float S1 = red[1] + red[3] + red[5] + red[7];
  float i0 = 1.f / S0, i1 = 1.f / S1;
  half8_t w0, w1;
#pragma unroll
  for (int j = 0; j < 8; ++j) {
    w0[j] = (_Float16)(e0[j] * i0);
    w1[j] = (_Float16)(e1[j] * i1);
  }
  *(half8_t*)&kT[r0] = w0;
  *(half8_t*)&kT[r1] = w1;
}

// ---------------------------------------------------------------------------
// kT [1024][4096] -> kh [4096][1024]  (fp16 tile transpose)
// ---------------------------------------------------------------------------
__global__ __launch_bounds__(256) void transpose_k(const _Float16* __restrict__ kT,
                                                   _Float16* __restrict__ kh) {
  __shared__ _Float16 T[64][65];
  int t0 = blockIdx.x * 64, d0 = blockIdx.y * 64;
  int t = threadIdx.x;
  int r = t >> 3, c8 = (t & 7) * 8;
#pragma unroll
  for (int p = 0; p < 2; ++p) {
    int dr = p * 32 + r;
    half8_t v = *(const half8_t*)&kT[(size_t)(d0 + dr) * MTOK + t0 + c8];
#pragma unroll
    for (int j = 0; j < 8; ++j) T[c8 + j][dr] = v[j];
  }
  __syncthreads();
#pragma unroll
  for (int p = 0; p < 2; ++p) {
    int tr = p * 32 + r;
    half8_t v;
#pragma unroll
    for (int j = 0; j < 8; ++j) v[j] = T[tr][c8 + j];
    *(half8_t*)&kh[(size_t)(t0 + tr) * KVD + d0 + c8] = v;
  }
}

// ---------------------------------------------------------------------------
// kvT[e][d] = sum_c v[c,e]*k[c,d] per (b,kvh,chunk). MFMA fp16, M=N=K=128.
// ---------------------------------------------------------------------------
__global__ __launch_bounds__(256) void kv_chunk_mfma(const _Float16* __restrict__ vT,
                                                     const _Float16* __restrict__ kT,
                                                     float* __restrict__ kvT) {
  __shared__ _Float16 As[2][128 * 32];
  __shared__ _Float16 Bs[2][128 * 32];
  int bi = blockIdx.x;
  int n = bi & 15, kvh = (bi >> 4) & 7, b = bi >> 7;
  int tok0 = b * SEQ + n * CHUNK;
  const int tid = threadIdx.x;
  const int lane = tid & 63;
  const int wave = tid >> 6;
  const int wr = wave & 1, wc = wave >> 1;
  const int m16 = lane & 15, quad = lane >> 4;
  const int qsw8 = (quad ^ ((m16 >> 1) & 3)) * 8;

  f32x4 acc[4][4];
#pragma unroll
  for (int i = 0; i < 4; ++i)
#pragma unroll
    for (int j = 0; j < 4; ++j) acc[i][j] = (f32x4){0.f, 0.f, 0.f, 0.f};

  const int r_ld = tid >> 2;
  const int sseg = (tid & 3) ^ ((tid >> 3) & 3);
  const size_t a_base = (size_t)(kvh * HD + r_ld) * MTOK + tok0 + sseg * 8;

#pragma unroll
  for (int i = 0; i < 2; ++i) {
    __builtin_amdgcn_global_load_lds(
        (const GLOBAL_AS void*)(vT + a_base + (size_t)i * 64 * MTOK),
        (LDS_AS void*)(&As[0][0] + i * 2048 + wave * 512), 16, 0, 0);
    __builtin_amdgcn_global_load_lds(
        (const GLOBAL_AS void*)(kT + a_base + (size_t)i * 64 * MTOK),
        (LDS_AS void*)(&Bs[0][0] + i * 2048 + wave * 512), 16, 0, 0);
  }

#pragma unroll
  for (int s = 0; s < 4; ++s) {
    WAITVM(0);
    BARX();
    if (s < 3) {
      const int k0 = (s + 1) * 32;
      const int bb = (s + 1) & 1;
#pragma unroll
      for (int i = 0; i < 2; ++i) {
        __builtin_amdgcn_global_load_lds(
            (const GLOBAL_AS void*)(vT + a_base + (size_t)i * 64 * MTOK + k0),
            (LDS_AS void*)(&As[bb][0] + i * 2048 + wave * 512), 16, 0, 0);
        __builtin_amdgcn_global_load_lds(
            (const GLOBAL_AS void*)(kT + a_base + (size_t)i * 64 * MTOK + k0),
            (LDS_AS void*)(&Bs[bb][0] + i * 2048 + wave * 512), 16, 0, 0);
      }
    }
    const _Float16* ra = &As[s & 1][0];
    const _Float16* rb = &Bs[s & 1][0];
    half8_t af[4], bf[4];
#pragma unroll
    for (int i = 0; i < 4; ++i) {
      af[i] = *(const half8_t*)&ra[(wr * 64 + i * 16 + m16) * 32 + qsw8];
      bf[i] = *(const half8_t*)&rb[(wc * 64 + i * 16 + m16) * 32 + qsw8];
    }
#pragma unroll
    for (int i = 0; i < 4; ++i)
#pragma unroll
      for (int j = 0; j < 4; ++j)
        acc[i][j] = __builtin_amdgcn_mfma_f32_16x16x32_f16(af[i], bf[j], acc[i][j], 0, 0, 0);
  }
#pragma unroll
  for (int i = 0; i < 4; ++i)
#pragma unroll
    for (int j = 0; j < 4; ++j) {
      int col = wc * 64 + j * 16 + m16;
      int rowb = wr * 64 + i * 16 + quad * 4;
#pragma unroll
      for (int r = 0; r < 4; ++r)
        kvT[(size_t)bi * 16384 + (size_t)(rowb + r) * 128 + col] = acc[i][j][r];
    }
}

// ---------------------------------------------------------------------------
// Exclusive chunk-cumsum of kvT (f32), emitting fp16 cumT. grid 1024x256.
// ---------------------------------------------------------------------------
__global__ __launch_bounds__(256) void cumsum_h(const float* __restrict__ kvT,
                                                _Float16* __restrict__ cumh) {
  int gid = blockIdx.x * 256 + threadIdx.x;
  int bk = gid >> 14, idx = gid & 16383;
  size_t base = (size_t)bk * NCHUNK * 16384 + idx;
  float run = 0.f;
#pragma unroll
  for (int n = 0; n < NCHUNK; ++n) {
    cumh[base + (size_t)n * 16384] = (_Float16)run;
    run += kvT[base + (size_t)n * 16384];
  }
}

// ---------------------------------------------------------------------------
// Fused scores+output per (b,h,chunk). v3 (round-7 verified): 8 uniform steps,
// dual-B in steps 0-3 (shared q fragments), Qs/Ss aliased. LDS 64 KB.
// ---------------------------------------------------------------------------
__global__ __launch_bounds__(256) void attn_fused(const _Float16* __restrict__ qh,
                                                  const _Float16* __restrict__ kh,
                                                  const _Float16* __restrict__ cumh,
                                                  const _Float16* __restrict__ vT,
                                                  _Float16* __restrict__ ath) {
  __shared__ _Float16 QS[128 * 128];   // Qs for steps 0-3, then Ss for 4-7
  __shared__ _Float16 Bk[2][128 * 32];
  __shared__ _Float16 Bc[2][128 * 32];
  int bi = blockIdx.x;
  int n = bi & 15, h = (bi >> 4) & 15, b = bi >> 8;
  int kvh = h >> 1;
  int tok0 = b * SEQ + n * CHUNK;
  const int tid = threadIdx.x;
  const int lane = tid & 63;
  const int wave = tid >> 6;
  const int wr = wave & 1, wc = wave >> 1;
  const int m16 = lane & 15, quad = lane >> 4;
  const int qsw8 = (quad ^ ((m16 >> 1) & 3)) * 8;
  const int r_ld = tid >> 2;
  const int sseg = (tid & 3) ^ ((tid >> 3) & 3);

  f32x4 acc[4][4];   // output accumulator (inter + intra)
  f32x4 accs[4][4];  // scores accumulator
#pragma unroll
  for (int i = 0; i < 4; ++i)
#pragma unroll
    for (int j = 0; j < 4; ++j) {
      acc[i][j] = (f32x4){0.f, 0.f, 0.f, 0.f};
      accs[i][j] = (f32x4){0.f, 0.f, 0.f, 0.f};
    }

  const int qrow = tid >> 4;
  const int qsl = (tid & 15) ^ (qrow & 7);
  const size_t qsrc = (size_t)(tok0 + qrow) * DIMV + h * HD + qsl * 8;
#pragma unroll
  for (int p = 0; p < 8; ++p)
    __builtin_amdgcn_global_load_lds(
        (const GLOBAL_AS void*)(qh + qsrc + (size_t)p * 16 * DIMV),
        (LDS_AS void*)(QS + p * 2048 + wave * 512), 16, 0, 0);

  const size_t kbase = (size_t)(tok0 + r_ld) * KVD + kvh * HD + sseg * 8;
  const size_t cbase = ((size_t)((b * 8 + kvh) * 16 + n)) * 16384 + (size_t)r_ld * 128 + sseg * 8;
  const size_t vbase = (size_t)(kvh * HD + r_ld) * MTOK + tok0 + sseg * 8;

#pragma unroll
  for (int i = 0; i < 2; ++i) {
    __builtin_amdgcn_global_load_lds(
        (const GLOBAL_AS void*)(kh + kbase + (size_t)i * 64 * KVD),
        (LDS_AS void*)(&Bk[0][0] + i * 2048 + wave * 512), 16, 0, 0);
    __builtin_amdgcn_global_load_lds(
        (const GLOBAL_AS void*)(cumh + cbase + (size_t)i * 64 * 128),
        (LDS_AS void*)(&Bc[0][0] + i * 2048 + wave * 512), 16, 0, 0);
  }

#pragma unroll
  for (int s = 0; s < 8; ++s) {
    WAITVM(0);
    BARX();
    if (s < 3) {
      const int k0 = (s + 1) * 32;
      const int bb = (s + 1) & 1;
#pragma unroll
      for (int i = 0; i < 2; ++i) {
        __builtin_amdgcn_global_load_lds(
            (const GLOBAL_AS void*)(kh + kbase + (size_t)i * 64 * KVD + k0),
            (LDS_AS void*)(&Bk[bb][0] + i * 2048 + wave * 512), 16, 0, 0);
        __builtin_amdgcn_global_load_lds(
            (const GLOBAL_AS void*)(cumh + cbase + (size_t)i * 64 * 128 + k0),
            (LDS_AS void*)(&Bc[bb][0] + i * 2048 + wave * 512), 16, 0, 0);
      }
    } else if (s < 7) {
      const int k0 = (s - 3) * 32;
      const int bb = (s + 1) & 1;
#pragma unroll
      for (int i = 0; i < 2; ++i)
        __builtin_amdgcn_global_load_lds(
            (const GLOBAL_AS void*)(vT + vbase + (size_t)i * 64 * MTOK + k0),
            (LDS_AS void*)(&Bk[bb][0] + i * 2048 + wave * 512), 16, 0, 0);
    }
    if (s < 4) {
      half8_t af[4], bfk[4], bfc[4];
      const int sl4 = s * 4;
      const _Float16* rk = &Bk[s & 1][0];
      const _Float16* rc = &Bc[s & 1][0];
#pragma unroll
      for (int i = 0; i < 4; ++i) {
        int row = wr * 64 + i * 16 + m16;
        af[i] = *(const half8_t*)&QS[row * 128 + ((sl4 + quad) ^ (m16 & 7)) * 8];
        bfk[i] = *(const half8_t*)&rk[(wc * 64 + i * 16 + m16) * 32 + qsw8];
        bfc[i] = *(const half8_t*)&rc[(wc * 64 + i * 16 + m16) * 32 + qsw8];
      }
#pragma unroll
      for (int i = 0; i < 4; ++i)
#pragma unroll
        for (int j = 0; j < 4; ++j) {
          accs[i][j] = __builtin_amdgcn_mfma_f32_16x16x32_f16(af[i], bfk[j], accs[i][j], 0, 0, 0);
          acc[i][j] = __builtin_amdgcn_mfma_f32_16x16x32_f16(af[i], bfc[j], acc[i][j], 0, 0, 0);
        }
      if (s == 3) {
        BARX();  // all waves done reading QS (q) before aliasing it with Ss
#pragma unroll
        for (int i = 0; i < 4; ++i)
#pragma unroll
          for (int j = 0; j < 4; ++j) {
            int col = wc * 64 + j * 16 + m16;
            int rowb = wr * 64 + i * 16 + quad * 4;
#pragma unroll
            for (int r = 0; r < 4; ++r) {
              int row = rowb + r;
              float v = (col <= row) ? accs[i][j][r] : 0.f;
              int sp = (col >> 3) ^ (row & 7);
              QS[row * 128 + sp * 8 + (col & 7)] = (_Float16)v;
            }
          }
        WAITL(0);  // drain Ss writes before next step's barrier publishes them
      }
    } else {
      half8_t af[4], bf[4];
      const int sl4 = (s - 4) * 4;
      const _Float16* rk = &Bk[s & 1][0];
#pragma unroll
      for (int i = 0; i < 4; ++i) {
        int row = wr * 64 + i * 16 + m16;
        af[i] = *(const half8_t*)&QS[row * 128 + ((sl4 + quad) ^ (m16 & 7)) * 8];
        bf[i] = *(const half8_t*)&rk[(wc * 64 + i * 16 + m16) * 32 + qsw8];
      }
#pragma unroll
      for (int i = 0; i < 4; ++i)
#pragma unroll
        for (int j = 0; j < 4; ++j)
          acc[i][j] = __builtin_amdgcn_mfma_f32_16x16x32_f16(af[i], bf[j], acc[i][j], 0, 0, 0);
    }
  }

#pragma unroll
  for (int i = 0; i < 4; ++i)
#pragma unroll
    for (int j = 0; j < 4; ++j) {
      int col = wc * 64 + j * 16 + m16;
      int rowb = wr * 64 + i * 16 + quad * 4;
#pragma unroll
      for (int r = 0; r < 4; ++r)
        ath[(size_t)(tok0 + rowb + r) * DIMV + h * HD + col] = (_Float16)acc[i][j][r];
    }
}

// ---------------------------------------------------------------------------
extern "C" void kernel_launch(void* const* d_in, const int* in_sizes, int n_in,
                              void* d_out, int out_size, void* d_ws, size_t ws_size,
                              hipStream_t stream) {
  const float* x  = (const float*)d_in[0];
  const float* fc = (const float*)d_in[1];
  const float* wq = (const float*)d_in[2];
  const float* wk = (const float*)d_in[3];
  const float* wv = (const float*)d_in[4];
  const float* wo = (const float*)d_in[5];
  float* out = (float*)d_out;

  char* p = (char*)d_ws;
  _Float16* xh    = (_Float16*)p;  p += 16777216;  // 4096x2048
  _Float16* wqkvh = (_Float16*)p;  p += 16777216;  // 4096x2048 (wq|wk|wv)
  _Float16* woh   = (_Float16*)p;  p += 8388608;   // 2048x2048
  _Float16* qh    = (_Float16*)p;  p += 16777216;  // 4096x2048
  _Float16* kT    = (_Float16*)p;  p += 8388608;   // 1024x4096
  _Float16* kh    = (_Float16*)p;  p += 8388608;   // 4096x1024
  _Float16* vT    = (_Float16*)p;  p += 8388608;   // 1024x4096
  float*    kvT   = (float*)p;     p += 16777216;  // 256x128x128 f32
  _Float16* cumh  = (_Float16*)p;  p += 8388608;
  _Float16* ath   = (_Float16*)p;  p += 16777216;  // 4096x2048
  float*    fcT   = (float*)p;     p += 1048576;   // 128x2048 f32

  // casts + fc transpose in one launch
  cast_all<<<10304, 256, 0, stream>>>(x, wq, wk, wv, wo, xh, wqkvh, woh, fc, fcT);

  // fused QKV projection + q RoPE/softmax (v2: 2-phase K-tiles, 32-MFMA clusters)
  hgemm_qkv_8p<<<dim3(16, 16), 512, 0, stream>>>(xh, wqkvh, fc, qh, kT, vT);

  // k rope + softmax, then transpose to token-major
  k_rope_softmax_T<<<1024, 256, 0, stream>>>(kT, fcT);
  transpose_k<<<dim3(64, 16), 256, 0, stream>>>(kT, kh);

  // chunked linear attention
  kv_chunk_mfma<<<256, 256, 0, stream>>>(vT, kT, kvT);
  cumsum_h<<<1024, 256, 0, stream>>>(kvT, cumh);

  // fused attention core (v3: 8 steps, dual-B, Qs/Ss aliased)
  attn_fused<<<512, 256, 0, stream>>>(qh, kh, cumh, vT, ath);

  // output projection
  hgemm_bt_8p<<<dim3(8, 32), 512, 0, stream>>>(ath, woh, out);
}